// Round 3
// baseline (3042.309 us; speedup 1.0000x reference)
//
#include <hip/hip_runtime.h>
#include <hip/hip_bf16.h>

typedef __hip_bfloat16 bf16;

constexpr int kB = 2;
constexpr int kS = 1024;
constexpr int kD = 512;
constexpr int kH = 8;
constexpr int kDK = 64;
constexpr int kL = 4;
constexpr int kV = 32000;
constexpr int kM = kB * kS;  // 2048 rows

// ---------------------------------------------------------------- embed + PE
__global__ __launch_bounds__(256)
void embed_kernel(const int* __restrict__ tokens, const float* __restrict__ emb,
                  float* __restrict__ x) {
  const int row = blockIdx.x;            // b*S + s
  const int s = row & (kS - 1);
  const int tok = tokens[row];
  const float scl = sqrtf((float)kD);    // sqrt(512), applied AFTER adding pe (faithful)
  for (int d = threadIdx.x; d < kD; d += 256) {
    float e = emb[(size_t)tok * kD + d];
    float den = powf(10000.0f, 2.0f * (float)d / (float)kD);
    float ang = (float)s / den;
    float pe = ((d & 1) == 0) ? sinf(ang) : cosf(ang);
    x[(size_t)row * kD + d] = (e + pe) * scl;
  }
}

// --------------------------------------------- generic tiled GEMM: C = A @ W
// A: fp32 [M x K] row-major.  WT==0: W fp32 [K x N] row-major.
// WT==1: W fp32 [N x K] row-major (C = A @ W^T), used for x @ emb.T.
template <int WT, int HAS_BIAS, int RELU>
__global__ __launch_bounds__(256)
void gemm_kernel(const float* __restrict__ A, const float* __restrict__ Wm,
                 float* __restrict__ Cout, const float* __restrict__ bias,
                 int Mdim, int Ndim, int Kdim) {
  __shared__ float As[16][68];
  __shared__ float Ws[16][68];
  const int m0 = blockIdx.x * 64;
  const int n0 = blockIdx.y * 64;
  const int t = threadIdx.x;
  const int tm = t >> 4, tn = t & 15;
  float acc[4][4] = {{0.f,0.f,0.f,0.f},{0.f,0.f,0.f,0.f},{0.f,0.f,0.f,0.f},{0.f,0.f,0.f,0.f}};
  const int mm = t >> 2, kq = t & 3;
  for (int k0 = 0; k0 < Kdim; k0 += 16) {
    {
      float4 a4 = *reinterpret_cast<const float4*>(&A[(size_t)(m0 + mm) * Kdim + k0 + kq * 4]);
      As[kq * 4 + 0][mm] = a4.x; As[kq * 4 + 1][mm] = a4.y;
      As[kq * 4 + 2][mm] = a4.z; As[kq * 4 + 3][mm] = a4.w;
    }
    if (WT == 0) {
      const int kk = t >> 4, nq = (t & 15) * 4;
      float4 w4 = *reinterpret_cast<const float4*>(&Wm[(size_t)(k0 + kk) * Ndim + n0 + nq]);
      Ws[kk][nq + 0] = w4.x; Ws[kk][nq + 1] = w4.y;
      Ws[kk][nq + 2] = w4.z; Ws[kk][nq + 3] = w4.w;
    } else {
      const int nn = t >> 2, kq2 = t & 3;
      float4 w4 = *reinterpret_cast<const float4*>(&Wm[(size_t)(n0 + nn) * Kdim + k0 + kq2 * 4]);
      Ws[kq2 * 4 + 0][nn] = w4.x; Ws[kq2 * 4 + 1][nn] = w4.y;
      Ws[kq2 * 4 + 2][nn] = w4.z; Ws[kq2 * 4 + 3][nn] = w4.w;
    }
    __syncthreads();
#pragma unroll
    for (int kk = 0; kk < 16; ++kk) {
      float4 av = *reinterpret_cast<const float4*>(&As[kk][tm * 4]);
      float4 bv = *reinterpret_cast<const float4*>(&Ws[kk][tn * 4]);
      acc[0][0] += av.x * bv.x; acc[0][1] += av.x * bv.y; acc[0][2] += av.x * bv.z; acc[0][3] += av.x * bv.w;
      acc[1][0] += av.y * bv.x; acc[1][1] += av.y * bv.y; acc[1][2] += av.y * bv.z; acc[1][3] += av.y * bv.w;
      acc[2][0] += av.z * bv.x; acc[2][1] += av.z * bv.y; acc[2][2] += av.z * bv.z; acc[2][3] += av.z * bv.w;
      acc[3][0] += av.w * bv.x; acc[3][1] += av.w * bv.y; acc[3][2] += av.w * bv.z; acc[3][3] += av.w * bv.w;
    }
    __syncthreads();
  }
#pragma unroll
  for (int i = 0; i < 4; ++i) {
    const int m = m0 + tm * 4 + i;
    float c[4];
#pragma unroll
    for (int j = 0; j < 4; ++j) {
      c[j] = acc[i][j];
      if (HAS_BIAS) c[j] += bias[n0 + tn * 4 + j];
      if (RELU) c[j] = fmaxf(c[j], 0.0f);
    }
    *reinterpret_cast<float4*>(&Cout[(size_t)m * Ndim + n0 + tn * 4]) =
        make_float4(c[0], c[1], c[2], c[3]);
  }
}

// ------------------------------------------------------------ QKV projection
// grid (M/64, H, 3).  W[h]: [D x DK] row-major block.  out layout [B,H,S,DK].
__global__ __launch_bounds__(256)
void qkv_kernel(const float* __restrict__ A, const float* __restrict__ Wqp,
                const float* __restrict__ Wkp, const float* __restrict__ Wvp,
                float* __restrict__ qo, float* __restrict__ ko, float* __restrict__ vo) {
  __shared__ float As[16][68];
  __shared__ float Ws[16][68];
  const int m0 = blockIdx.x * 64;
  const int h = blockIdx.y;
  const int mat = blockIdx.z;
  const float* Wm = (mat == 0 ? Wqp : (mat == 1 ? Wkp : Wvp)) + (size_t)h * kD * kDK;
  float* Out = (mat == 0 ? qo : (mat == 1 ? ko : vo));
  const int t = threadIdx.x;
  const int tm = t >> 4, tn = t & 15;
  float acc[4][4] = {{0.f,0.f,0.f,0.f},{0.f,0.f,0.f,0.f},{0.f,0.f,0.f,0.f},{0.f,0.f,0.f,0.f}};
  const int mm = t >> 2, kq = t & 3;
  for (int k0 = 0; k0 < kD; k0 += 16) {
    {
      float4 a4 = *reinterpret_cast<const float4*>(&A[(size_t)(m0 + mm) * kD + k0 + kq * 4]);
      As[kq * 4 + 0][mm] = a4.x; As[kq * 4 + 1][mm] = a4.y;
      As[kq * 4 + 2][mm] = a4.z; As[kq * 4 + 3][mm] = a4.w;
    }
    {
      const int kk = t >> 4, nq = (t & 15) * 4;
      float4 w4 = *reinterpret_cast<const float4*>(&Wm[(size_t)(k0 + kk) * kDK + nq]);
      Ws[kk][nq + 0] = w4.x; Ws[kk][nq + 1] = w4.y;
      Ws[kk][nq + 2] = w4.z; Ws[kk][nq + 3] = w4.w;
    }
    __syncthreads();
#pragma unroll
    for (int kk = 0; kk < 16; ++kk) {
      float4 av = *reinterpret_cast<const float4*>(&As[kk][tm * 4]);
      float4 bv = *reinterpret_cast<const float4*>(&Ws[kk][tn * 4]);
      acc[0][0] += av.x * bv.x; acc[0][1] += av.x * bv.y; acc[0][2] += av.x * bv.z; acc[0][3] += av.x * bv.w;
      acc[1][0] += av.y * bv.x; acc[1][1] += av.y * bv.y; acc[1][2] += av.y * bv.z; acc[1][3] += av.y * bv.w;
      acc[2][0] += av.z * bv.x; acc[2][1] += av.z * bv.y; acc[2][2] += av.z * bv.z; acc[2][3] += av.z * bv.w;
      acc[3][0] += av.w * bv.x; acc[3][1] += av.w * bv.y; acc[3][2] += av.w * bv.z; acc[3][3] += av.w * bv.w;
    }
    __syncthreads();
  }
#pragma unroll
  for (int i = 0; i < 4; ++i) {
    const int m = m0 + tm * 4 + i;
    const int b_ = m >> 10, s = m & (kS - 1);
    float* op = &Out[((size_t)(b_ * kH + h) * kS + s) * kDK + tn * 4];
    *reinterpret_cast<float4*>(op) = make_float4(acc[i][0], acc[i][1], acc[i][2], acc[i][3]);
  }
}

// ---------------------------------------------------------- flash attention
// grid (S/32, B*H).  q/k/v: [B,H,S,DK] fp32.  out: [B,S,D] (head-concat).
// Non-causal (reference mask adds 1e-15 = fp32 no-op). Q pre-scaled by 1/8.
__global__ __launch_bounds__(256)
void attn_kernel(const float* __restrict__ qg, const float* __restrict__ kg,
                 const float* __restrict__ vg, float* __restrict__ out) {
  __shared__ float Qs[32][kDK + 4];
  __shared__ float Kst[kDK][64 + 4];  // transposed K tile: Kst[d][j]
  __shared__ float Vs[64][kDK + 4];
  __shared__ float Ps[32][64 + 4];
  const int t = threadIdx.x;
  const int bh = blockIdx.y;
  const int s0 = blockIdx.x * 32;
  const size_t base = (size_t)bh * kS * kDK;
  {
    const int r2 = t >> 3, c2 = (t & 7) * 8;
    const float* src = &qg[base + (size_t)(s0 + r2) * kDK + c2];
    float4 a = *reinterpret_cast<const float4*>(src);
    float4 b = *reinterpret_cast<const float4*>(src + 4);
    Qs[r2][c2 + 0] = a.x * 0.125f; Qs[r2][c2 + 1] = a.y * 0.125f;
    Qs[r2][c2 + 2] = a.z * 0.125f; Qs[r2][c2 + 3] = a.w * 0.125f;
    Qs[r2][c2 + 4] = b.x * 0.125f; Qs[r2][c2 + 5] = b.y * 0.125f;
    Qs[r2][c2 + 6] = b.z * 0.125f; Qs[r2][c2 + 7] = b.w * 0.125f;
  }
  __syncthreads();
  const int r = t >> 3;   // 0..31 q-row in tile
  const int g = t & 7;    // 8 lanes cooperate per row
  float qreg[kDK];
#pragma unroll
  for (int d = 0; d < kDK; ++d) qreg[d] = Qs[r][d];
  float m_r = -1e30f, l_r = 0.0f;
  float acc[8] = {0.f,0.f,0.f,0.f,0.f,0.f,0.f,0.f};
  for (int kt = 0; kt < kS / 64; ++kt) {
    __syncthreads();  // previous PV reads done before overwriting K/V tiles
    {
      const int rr = t >> 2, cq = (t & 3) * 16;
      const float* ks = &kg[base + (size_t)(kt * 64 + rr) * kDK + cq];
      const float* vs = &vg[base + (size_t)(kt * 64 + rr) * kDK + cq];
#pragma unroll
      for (int ii = 0; ii < 4; ++ii) {
        float4 k4 = *reinterpret_cast<const float4*>(ks + ii * 4);
        Kst[cq + ii * 4 + 0][rr] = k4.x;
        Kst[cq + ii * 4 + 1][rr] = k4.y;
        Kst[cq + ii * 4 + 2][rr] = k4.z;
        Kst[cq + ii * 4 + 3][rr] = k4.w;
        float4 v4 = *reinterpret_cast<const float4*>(vs + ii * 4);
        *reinterpret_cast<float4*>(&Vs[rr][cq + ii * 4]) = v4;
      }
    }
    __syncthreads();
    float p[8] = {0.f,0.f,0.f,0.f,0.f,0.f,0.f,0.f};
#pragma unroll
    for (int d = 0; d < kDK; ++d) {
      const float qd = qreg[d];
      float4 kA = *reinterpret_cast<const float4*>(&Kst[d][g * 8]);
      float4 kB = *reinterpret_cast<const float4*>(&Kst[d][g * 8 + 4]);
      p[0] += qd * kA.x; p[1] += qd * kA.y; p[2] += qd * kA.z; p[3] += qd * kA.w;
      p[4] += qd * kB.x; p[5] += qd * kB.y; p[6] += qd * kB.z; p[7] += qd * kB.w;
    }
    float tmax = fmaxf(fmaxf(fmaxf(p[0], p[1]), fmaxf(p[2], p[3])),
                       fmaxf(fmaxf(p[4], p[5]), fmaxf(p[6], p[7])));
    tmax = fmaxf(tmax, __shfl_xor(tmax, 1));
    tmax = fmaxf(tmax, __shfl_xor(tmax, 2));
    tmax = fmaxf(tmax, __shfl_xor(tmax, 4));
    const float newm = fmaxf(m_r, tmax);
    const float corr = expf(m_r - newm);
    float tsum = 0.0f;
#pragma unroll
    for (int jj = 0; jj < 8; ++jj) { p[jj] = expf(p[jj] - newm); tsum += p[jj]; }
    tsum += __shfl_xor(tsum, 1);
    tsum += __shfl_xor(tsum, 2);
    tsum += __shfl_xor(tsum, 4);
    l_r = l_r * corr + tsum;
    m_r = newm;
#pragma unroll
    for (int cc = 0; cc < 8; ++cc) acc[cc] *= corr;
#pragma unroll
    for (int jj = 0; jj < 8; ++jj) Ps[r][g * 8 + jj] = p[jj];
    __syncthreads();
#pragma unroll 8
    for (int j = 0; j < 64; ++j) {
      const float pj = Ps[r][j];
      float4 v0 = *reinterpret_cast<const float4*>(&Vs[j][g * 8]);
      float4 v1 = *reinterpret_cast<const float4*>(&Vs[j][g * 8 + 4]);
      acc[0] += pj * v0.x; acc[1] += pj * v0.y; acc[2] += pj * v0.z; acc[3] += pj * v0.w;
      acc[4] += pj * v1.x; acc[5] += pj * v1.y; acc[6] += pj * v1.z; acc[7] += pj * v1.w;
    }
  }
  const int b_ = bh >> 3, h_ = bh & 7;
  const float invl = 1.0f / l_r;
  float* op = &out[((size_t)(b_ * kS + (s0 + r))) * kD + h_ * kDK + g * 8];
#pragma unroll
  for (int cc = 0; cc < 8; ++cc) op[cc] = acc[cc] * invl;
}

// --------------------------------------------- residual + LayerNorm in place
// x = gain/(std+eps) * (x + h - mean) + bias ; gain/bias are per (s, d), fp32.
__global__ __launch_bounds__(256)
void ln_kernel(float* __restrict__ x, const float* __restrict__ h,
               const float* __restrict__ gain, const float* __restrict__ bias) {
  const int row = blockIdx.x;
  const int s = row & (kS - 1);
  const int t = threadIdx.x;
  float* xr = x + (size_t)row * kD;
  const float* hr = h + (size_t)row * kD;
  const float v0 = xr[t] + hr[t];
  const float v1 = xr[t + 256] + hr[t + 256];
  float sum = v0 + v1;
  float sq = v0 * v0 + v1 * v1;
#pragma unroll
  for (int off = 1; off < 64; off <<= 1) {
    sum += __shfl_xor(sum, off);
    sq += __shfl_xor(sq, off);
  }
  __shared__ float rs[4], rq[4];
  if ((t & 63) == 0) { rs[t >> 6] = sum; rq[t >> 6] = sq; }
  __syncthreads();
  sum = rs[0] + rs[1] + rs[2] + rs[3];
  sq = rq[0] + rq[1] + rq[2] + rq[3];
  const float mean = sum * (1.0f / kD);
  const float var = fmaxf(sq * (1.0f / kD) - mean * mean, 0.0f);
  const float inv = 1.0f / (sqrtf(var) + 1e-6f);  // g/(std+EPS)
  const float* gr = gain + (size_t)s * kD;
  const float* br = bias + (size_t)s * kD;
  xr[t] = gr[t] * inv * (v0 - mean) + br[t];
  xr[t + 256] = gr[t + 256] * inv * (v1 - mean) + br[t + 256];
}

// ------------------------------------ final softmax over V, fp32 in place
__global__ __launch_bounds__(256)
void softmax_kernel(float* __restrict__ lg) {
  const int row = blockIdx.x;
  const int t = threadIdx.x;
  float* lr = lg + (size_t)row * kV;
  __shared__ float red[4];
  float mx = -1e30f;
  for (int i = t; i < kV; i += 256) mx = fmaxf(mx, lr[i]);
#pragma unroll
  for (int off = 1; off < 64; off <<= 1) mx = fmaxf(mx, __shfl_xor(mx, off));
  if ((t & 63) == 0) red[t >> 6] = mx;
  __syncthreads();
  mx = fmaxf(fmaxf(red[0], red[1]), fmaxf(red[2], red[3]));
  __syncthreads();
  float sum = 0.0f;
  for (int i = t; i < kV; i += 256) sum += expf(lr[i] - mx);
#pragma unroll
  for (int off = 1; off < 64; off <<= 1) sum += __shfl_xor(sum, off);
  if ((t & 63) == 0) red[t >> 6] = sum;
  __syncthreads();
  sum = red[0] + red[1] + red[2] + red[3];
  const float inv = 1.0f / sum;
  for (int i = t; i < kV; i += 256) lr[i] = expf(lr[i] - mx) * inv;
}

// ---------------------------------------------------------------------------
extern "C" void kernel_launch(void* const* d_in, const int* in_sizes, int n_in,
                              void* d_out, int out_size, void* d_ws, size_t ws_size,
                              hipStream_t stream) {
  (void)in_sizes; (void)n_in; (void)out_size; (void)ws_size;
  const int* tokens = (const int*)d_in[0];
  const float* emb = (const float*)d_in[1];
  const float* Wq = (const float*)d_in[2];
  const float* Wk = (const float*)d_in[3];
  const float* Wv = (const float*)d_in[4];
  const float* Wo = (const float*)d_in[5];
  const float* lng = (const float*)d_in[6];
  const float* lnb = (const float*)d_in[7];
  const float* w1 = (const float*)d_in[8];
  const float* b1 = (const float*)d_in[9];
  const float* w2 = (const float*)d_in[10];
  const float* b2 = (const float*)d_in[11];

  const size_t NA = (size_t)kM * kD;  // 1,048,576 floats = 4 MB
  float* x = (float*)d_ws;
  float* q = x + NA;
  float* k = q + NA;
  float* v = k + NA;
  float* ao = v + NA;
  float* t1 = ao + NA;

  embed_kernel<<<kM, 256, 0, stream>>>(tokens, emb, x);
  for (int l = 0; l < kL; ++l) {
    for (int j = 0; j < 2; ++j) {
      const size_t lj = (size_t)(l * 2 + j);
      qkv_kernel<<<dim3(kM / 64, kH, 3), 256, 0, stream>>>(
          x, Wq + lj * kH * kD * kDK, Wk + lj * kH * kD * kDK, Wv + lj * kH * kD * kDK,
          q, k, v);
      attn_kernel<<<dim3(kS / 32, kB * kH), 256, 0, stream>>>(q, k, v, ao);
      gemm_kernel<0, 0, 0><<<dim3(kM / 64, kD / 64), 256, 0, stream>>>(
          ao, Wo + lj * kD * kD, t1, nullptr, kM, kD, kD);
      ln_kernel<<<kM, 256, 0, stream>>>(x, t1, lng + (size_t)(l * 3 + j) * kS * kD,
                                        lnb + (size_t)(l * 3 + j) * kS * kD);
    }
    gemm_kernel<0, 1, 1><<<dim3(kM / 64, kD / 64), 256, 0, stream>>>(
        x, w1 + (size_t)l * kD * kD, t1, b1 + (size_t)l * kD, kM, kD, kD);
    gemm_kernel<0, 1, 0><<<dim3(kM / 64, kD / 64), 256, 0, stream>>>(
        t1, w2 + (size_t)l * kD * kD, ao, b2 + (size_t)l * kD, kM, kD, kD);
    ln_kernel<<<kM, 256, 0, stream>>>(x, ao, lng + (size_t)(l * 3 + 2) * kS * kD,
                                      lnb + (size_t)(l * 3 + 2) * kS * kD);
  }
  // logits = x @ emb.T  -> fp32, stored in d_out; softmax in place
  float* logits = (float*)d_out;
  gemm_kernel<1, 0, 0><<<dim3(kM / 64, kV / 64), 256, 0, stream>>>(
      x, emb, logits, nullptr, kM, kV, kD);
  softmax_kernel<<<kM, 256, 0, stream>>>(logits);
}

// Round 4
// 2010.422 us; speedup vs baseline: 1.5133x; 1.5133x over previous
//
#include <hip/hip_runtime.h>
#include <hip/hip_bf16.h>

typedef __hip_bfloat16 bf16;
typedef short bf16x8 __attribute__((ext_vector_type(8)));
typedef float f32x4 __attribute__((ext_vector_type(4)));
typedef unsigned short u16x4 __attribute__((ext_vector_type(4)));
typedef unsigned short u16x8 __attribute__((ext_vector_type(8)));

constexpr int kB = 2;
constexpr int kS = 1024;
constexpr int kD = 512;
constexpr int kH = 8;
constexpr int kDK = 64;
constexpr int kL = 4;
constexpr int kV = 32000;
constexpr int kM = kB * kS;  // 2048 rows

// bf16 round-to-nearest-even, manual (no header-version risk)
__device__ __forceinline__ unsigned short f2bh(float x) {
  unsigned u = __builtin_bit_cast(unsigned, x);
  unsigned r = u + 0x7fffu + ((u >> 16) & 1u);
  return (unsigned short)(r >> 16);
}
__device__ __forceinline__ float bh2f(unsigned short h) {
  return __builtin_bit_cast(float, (unsigned)h << 16);
}

// ---------------------------------------------------------------- embed + PE
__global__ __launch_bounds__(256)
void embed_kernel(const int* __restrict__ tokens, const float* __restrict__ emb,
                  float* __restrict__ x) {
  const int row = blockIdx.x;            // b*S + s
  const int s = row & (kS - 1);
  const int tok = tokens[row];
  const float scl = sqrtf((float)kD);    // applied AFTER adding pe (faithful)
  for (int d = threadIdx.x; d < kD; d += 256) {
    float e = emb[(size_t)tok * kD + d];
    float den = powf(10000.0f, 2.0f * (float)d / (float)kD);
    float ang = (float)s / den;
    float pe = ((d & 1) == 0) ? sinf(ang) : cosf(ang);
    x[(size_t)row * kD + d] = (e + pe) * scl;
  }
}

// --------------------------------------------------- MFMA split-bf16 GEMM
// MODE 0: C = A @ B, B fp32 [K][N] row-major.
// MODE 1: C = A @ B^T, B fp32 [N][K] row-major (vocab: emb).
// MODE 2: qkv — blockIdx.y = head, blockIdx.z selects (B0,C0)/(B1,C1)/(B2,C2);
//         B block = W + h*K*64 ([K][64] row-major); out layout [B,H,S,DK].
// SPLIT: 1 = plain bf16 (hi only), 3 = hi*hi + lo*hi + hi*lo (near-fp32).
// A fp32 [M][K]; C fp32. MFMA 16x16x32_bf16; LDS [m][k]/[n][k], k-stride 40.
template <int MODE, int BM, int BN, int SPLIT, int BIAS, int RELU>
__global__ __launch_bounds__(256)
void mgemm(const float* __restrict__ A,
           const float* __restrict__ B0, const float* __restrict__ B1,
           const float* __restrict__ B2,
           float* __restrict__ C0, float* __restrict__ C1, float* __restrict__ C2,
           const float* __restrict__ bias, int Mdim, int Ndim, int Kdim) {
  constexpr int LDK = 40;            // padded bf16 k-stride (80 B = 20 banks)
  constexpr int MF = BM / 32;        // 16-wide frags per wave (wave grid 2x2)
  constexpr int NF = BN / 32;
  __shared__ unsigned short Ah[BM * LDK];
  __shared__ unsigned short Bh[BN * LDK];
  __shared__ unsigned short Al[(SPLIT > 1 ? BM : 1) * LDK];
  __shared__ unsigned short Bl[(SPLIT > 1 ? BN : 1) * LDK];

  const int t = threadIdx.x;
  const int lane = t & 63;
  const int g = lane >> 4, li = lane & 15;
  const int w = t >> 6;
  const int wr = w >> 1, wc = w & 1;
  const int m0 = blockIdx.x * BM;
  int n0;
  const float* Bm;
  float* Cc;
  if (MODE == 2) {
    n0 = 0;
    const float* Ws = (blockIdx.z == 0) ? B0 : (blockIdx.z == 1) ? B1 : B2;
    Bm = Ws + (size_t)blockIdx.y * Kdim * 64;
    Cc = (blockIdx.z == 0) ? C0 : (blockIdx.z == 1) ? C1 : C2;
  } else {
    n0 = blockIdx.y * BN;
    Bm = B0;
    Cc = C0;
  }

  f32x4 acc[MF][NF];
#pragma unroll
  for (int i = 0; i < MF; ++i)
#pragma unroll
    for (int j = 0; j < NF; ++j) acc[i][j] = (f32x4){0.f, 0.f, 0.f, 0.f};

  for (int k0 = 0; k0 < Kdim; k0 += 32) {
    __syncthreads();
    // ---- stage A tile [BM][32] (contiguous float4 reads)
#pragma unroll
    for (int it = 0; it < BM / 32; ++it) {
      const int idx = it * 256 + t;
      const int row = idx >> 3, c4 = (idx & 7) * 4;
      float4 v = *reinterpret_cast<const float4*>(
          &A[(size_t)(m0 + row) * Kdim + k0 + c4]);
      u16x4 h;
      h[0] = f2bh(v.x); h[1] = f2bh(v.y); h[2] = f2bh(v.z); h[3] = f2bh(v.w);
      *reinterpret_cast<u16x4*>(&Ah[row * LDK + c4]) = h;
      if (SPLIT > 1) {
        u16x4 lo;
        lo[0] = f2bh(v.x - bh2f(h[0])); lo[1] = f2bh(v.y - bh2f(h[1]));
        lo[2] = f2bh(v.z - bh2f(h[2])); lo[3] = f2bh(v.w - bh2f(h[3]));
        *reinterpret_cast<u16x4*>(&Al[row * LDK + c4]) = lo;
      }
    }
    // ---- stage B tile to LDS [n][k]
    if (MODE == 1) {
      // B rows are n: contiguous float4 reads along k
#pragma unroll
      for (int it = 0; it < BN / 32; ++it) {
        const int idx = it * 256 + t;
        const int row = idx >> 3, c4 = (idx & 7) * 4;
        float4 v = *reinterpret_cast<const float4*>(
            &B0[(size_t)(n0 + row) * Kdim + k0 + c4]);
        u16x4 h;
        h[0] = f2bh(v.x); h[1] = f2bh(v.y); h[2] = f2bh(v.z); h[3] = f2bh(v.w);
        *reinterpret_cast<u16x4*>(&Bh[row * LDK + c4]) = h;
        if (SPLIT > 1) {
          u16x4 lo;
          lo[0] = f2bh(v.x - bh2f(h[0])); lo[1] = f2bh(v.y - bh2f(h[1]));
          lo[2] = f2bh(v.z - bh2f(h[2])); lo[3] = f2bh(v.w - bh2f(h[3]));
          *reinterpret_cast<u16x4*>(&Bl[row * LDK + c4]) = lo;
        }
      }
    } else {
      // B is [K][N]: lane-per-column (coalesced in n), strided in k
      constexpr int KPER = 32 * BN / 256;  // 8 (BN=64) or 16 (BN=128)
      const int n = t & (BN - 1);
      const int kb = (t / BN) * KPER;
      float xs[KPER];
#pragma unroll
      for (int i = 0; i < KPER; ++i)
        xs[i] = Bm[(size_t)(k0 + kb + i) * Ndim + n0 + n];
#pragma unroll
      for (int ch = 0; ch < KPER / 8; ++ch) {
        u16x8 h, lo;
#pragma unroll
        for (int i = 0; i < 8; ++i) {
          float xv = xs[ch * 8 + i];
          h[i] = f2bh(xv);
          if (SPLIT > 1) lo[i] = f2bh(xv - bh2f(h[i]));
        }
        *reinterpret_cast<u16x8*>(&Bh[n * LDK + kb + ch * 8]) = h;
        if (SPLIT > 1)
          *reinterpret_cast<u16x8*>(&Bl[n * LDK + kb + ch * 8]) = lo;
      }
    }
    __syncthreads();
    // ---- fragments + MFMA
    bf16x8 fah[MF], fal[MF], fbh[NF], fbl[NF];
#pragma unroll
    for (int fm = 0; fm < MF; ++fm) {
      const int off = (wr * (BM / 2) + fm * 16 + li) * LDK + g * 8;
      fah[fm] = *reinterpret_cast<const bf16x8*>(&Ah[off]);
      if (SPLIT > 1) fal[fm] = *reinterpret_cast<const bf16x8*>(&Al[off]);
    }
#pragma unroll
    for (int fn = 0; fn < NF; ++fn) {
      const int off = (wc * (BN / 2) + fn * 16 + li) * LDK + g * 8;
      fbh[fn] = *reinterpret_cast<const bf16x8*>(&Bh[off]);
      if (SPLIT > 1) fbl[fn] = *reinterpret_cast<const bf16x8*>(&Bl[off]);
    }
#pragma unroll
    for (int fm = 0; fm < MF; ++fm)
#pragma unroll
      for (int fn = 0; fn < NF; ++fn) {
        acc[fm][fn] = __builtin_amdgcn_mfma_f32_16x16x32_bf16(
            fah[fm], fbh[fn], acc[fm][fn], 0, 0, 0);
        if (SPLIT > 1) {
          acc[fm][fn] = __builtin_amdgcn_mfma_f32_16x16x32_bf16(
              fal[fm], fbh[fn], acc[fm][fn], 0, 0, 0);
          acc[fm][fn] = __builtin_amdgcn_mfma_f32_16x16x32_bf16(
              fah[fm], fbl[fn], acc[fm][fn], 0, 0, 0);
        }
      }
  }
  // ---- epilogue: D col = lane&15, row = (lane>>4)*4 + reg
#pragma unroll
  for (int fm = 0; fm < MF; ++fm)
#pragma unroll
    for (int fn = 0; fn < NF; ++fn)
#pragma unroll
      for (int r = 0; r < 4; ++r) {
        const int m = m0 + wr * (BM / 2) + fm * 16 + g * 4 + r;
        const int n = n0 + wc * (BN / 2) + fn * 16 + li;
        float c = acc[fm][fn][r];
        if (BIAS) c += bias[n];
        if (RELU) c = fmaxf(c, 0.0f);
        if (MODE == 2) {
          const int b_ = m >> 10, s = m & (kS - 1);
          Cc[((size_t)(b_ * kH + blockIdx.y) * kS + s) * kDK + n] = c;
        } else {
          Cc[(size_t)m * Ndim + n] = c;
        }
      }
}

// ---------------------------------------------------------- flash attention
// grid (S/32, B*H).  q/k/v: [B,H,S,DK] fp32.  out: [B,S,D] (head-concat).
// Non-causal (reference mask adds 1e-15 = fp32 no-op). Q pre-scaled by 1/8.
__global__ __launch_bounds__(256)
void attn_kernel(const float* __restrict__ qg, const float* __restrict__ kg,
                 const float* __restrict__ vg, float* __restrict__ out) {
  __shared__ float Qs[32][kDK + 4];
  __shared__ float Kst[kDK][64 + 4];  // transposed K tile: Kst[d][j]
  __shared__ float Vs[64][kDK + 4];
  __shared__ float Ps[32][64 + 4];
  const int t = threadIdx.x;
  const int bh = blockIdx.y;
  const int s0 = blockIdx.x * 32;
  const size_t base = (size_t)bh * kS * kDK;
  {
    const int r2 = t >> 3, c2 = (t & 7) * 8;
    const float* src = &qg[base + (size_t)(s0 + r2) * kDK + c2];
    float4 a = *reinterpret_cast<const float4*>(src);
    float4 b = *reinterpret_cast<const float4*>(src + 4);
    Qs[r2][c2 + 0] = a.x * 0.125f; Qs[r2][c2 + 1] = a.y * 0.125f;
    Qs[r2][c2 + 2] = a.z * 0.125f; Qs[r2][c2 + 3] = a.w * 0.125f;
    Qs[r2][c2 + 4] = b.x * 0.125f; Qs[r2][c2 + 5] = b.y * 0.125f;
    Qs[r2][c2 + 6] = b.z * 0.125f; Qs[r2][c2 + 7] = b.w * 0.125f;
  }
  __syncthreads();
  const int r = t >> 3;   // 0..31 q-row in tile
  const int g = t & 7;    // 8 lanes cooperate per row
  float qreg[kDK];
#pragma unroll
  for (int d = 0; d < kDK; ++d) qreg[d] = Qs[r][d];
  float m_r = -1e30f, l_r = 0.0f;
  float acc[8] = {0.f,0.f,0.f,0.f,0.f,0.f,0.f,0.f};
  for (int kt = 0; kt < kS / 64; ++kt) {
    __syncthreads();
    {
      const int rr = t >> 2, cq = (t & 3) * 16;
      const float* ks = &kg[base + (size_t)(kt * 64 + rr) * kDK + cq];
      const float* vs = &vg[base + (size_t)(kt * 64 + rr) * kDK + cq];
#pragma unroll
      for (int ii = 0; ii < 4; ++ii) {
        float4 k4 = *reinterpret_cast<const float4*>(ks + ii * 4);
        Kst[cq + ii * 4 + 0][rr] = k4.x;
        Kst[cq + ii * 4 + 1][rr] = k4.y;
        Kst[cq + ii * 4 + 2][rr] = k4.z;
        Kst[cq + ii * 4 + 3][rr] = k4.w;
        float4 v4 = *reinterpret_cast<const float4*>(vs + ii * 4);
        *reinterpret_cast<float4*>(&Vs[rr][cq + ii * 4]) = v4;
      }
    }
    __syncthreads();
    float p[8] = {0.f,0.f,0.f,0.f,0.f,0.f,0.f,0.f};
#pragma unroll
    for (int d = 0; d < kDK; ++d) {
      const float qd = qreg[d];
      float4 kA = *reinterpret_cast<const float4*>(&Kst[d][g * 8]);
      float4 kB = *reinterpret_cast<const float4*>(&Kst[d][g * 8 + 4]);
      p[0] += qd * kA.x; p[1] += qd * kA.y; p[2] += qd * kA.z; p[3] += qd * kA.w;
      p[4] += qd * kB.x; p[5] += qd * kB.y; p[6] += qd * kB.z; p[7] += qd * kB.w;
    }
    float tmax = fmaxf(fmaxf(fmaxf(p[0], p[1]), fmaxf(p[2], p[3])),
                       fmaxf(fmaxf(p[4], p[5]), fmaxf(p[6], p[7])));
    tmax = fmaxf(tmax, __shfl_xor(tmax, 1));
    tmax = fmaxf(tmax, __shfl_xor(tmax, 2));
    tmax = fmaxf(tmax, __shfl_xor(tmax, 4));
    const float newm = fmaxf(m_r, tmax);
    const float corr = expf(m_r - newm);
    float tsum = 0.0f;
#pragma unroll
    for (int jj = 0; jj < 8; ++jj) { p[jj] = expf(p[jj] - newm); tsum += p[jj]; }
    tsum += __shfl_xor(tsum, 1);
    tsum += __shfl_xor(tsum, 2);
    tsum += __shfl_xor(tsum, 4);
    l_r = l_r * corr + tsum;
    m_r = newm;
#pragma unroll
    for (int cc = 0; cc < 8; ++cc) acc[cc] *= corr;
#pragma unroll
    for (int jj = 0; jj < 8; ++jj) Ps[r][g * 8 + jj] = p[jj];
    __syncthreads();
#pragma unroll 8
    for (int j = 0; j < 64; ++j) {
      const float pj = Ps[r][j];
      float4 v0 = *reinterpret_cast<const float4*>(&Vs[j][g * 8]);
      float4 v1 = *reinterpret_cast<const float4*>(&Vs[j][g * 8 + 4]);
      acc[0] += pj * v0.x; acc[1] += pj * v0.y; acc[2] += pj * v0.z; acc[3] += pj * v0.w;
      acc[4] += pj * v1.x; acc[5] += pj * v1.y; acc[6] += pj * v1.z; acc[7] += pj * v1.w;
    }
  }
  const int b_ = bh >> 3, h_ = bh & 7;
  const float invl = 1.0f / l_r;
  float* op = &out[((size_t)(b_ * kS + (s0 + r))) * kD + h_ * kDK + g * 8];
#pragma unroll
  for (int cc = 0; cc < 8; ++cc) op[cc] = acc[cc] * invl;
}

// --------------------------------------------- residual + LayerNorm in place
__global__ __launch_bounds__(256)
void ln_kernel(float* __restrict__ x, const float* __restrict__ h,
               const float* __restrict__ gain, const float* __restrict__ bias) {
  const int row = blockIdx.x;
  const int s = row & (kS - 1);
  const int t = threadIdx.x;
  float* xr = x + (size_t)row * kD;
  const float* hr = h + (size_t)row * kD;
  const float v0 = xr[t] + hr[t];
  const float v1 = xr[t + 256] + hr[t + 256];
  float sum = v0 + v1;
  float sq = v0 * v0 + v1 * v1;
#pragma unroll
  for (int off = 1; off < 64; off <<= 1) {
    sum += __shfl_xor(sum, off);
    sq += __shfl_xor(sq, off);
  }
  __shared__ float rs[4], rq[4];
  if ((t & 63) == 0) { rs[t >> 6] = sum; rq[t >> 6] = sq; }
  __syncthreads();
  sum = rs[0] + rs[1] + rs[2] + rs[3];
  sq = rq[0] + rq[1] + rq[2] + rq[3];
  const float mean = sum * (1.0f / kD);
  const float var = fmaxf(sq * (1.0f / kD) - mean * mean, 0.0f);
  const float inv = 1.0f / (sqrtf(var) + 1e-6f);  // g/(std+EPS)
  const float* gr = gain + (size_t)s * kD;
  const float* br = bias + (size_t)s * kD;
  xr[t] = gr[t] * inv * (v0 - mean) + br[t];
  xr[t + 256] = gr[t + 256] * inv * (v1 - mean) + br[t + 256];
}

// ------------------------------------ final softmax over V, fp32 in place
__global__ __launch_bounds__(256)
void softmax_kernel(float* __restrict__ lg) {
  const int row = blockIdx.x;
  const int t = threadIdx.x;
  float* lr = lg + (size_t)row * kV;
  __shared__ float red[4];
  float mx = -1e30f;
  for (int i = t; i < kV; i += 256) mx = fmaxf(mx, lr[i]);
#pragma unroll
  for (int off = 1; off < 64; off <<= 1) mx = fmaxf(mx, __shfl_xor(mx, off));
  if ((t & 63) == 0) red[t >> 6] = mx;
  __syncthreads();
  mx = fmaxf(fmaxf(red[0], red[1]), fmaxf(red[2], red[3]));
  __syncthreads();
  float sum = 0.0f;
  for (int i = t; i < kV; i += 256) sum += expf(lr[i] - mx);
#pragma unroll
  for (int off = 1; off < 64; off <<= 1) sum += __shfl_xor(sum, off);
  if ((t & 63) == 0) red[t >> 6] = sum;
  __syncthreads();
  sum = red[0] + red[1] + red[2] + red[3];
  const float inv = 1.0f / sum;
  for (int i = t; i < kV; i += 256) lr[i] = expf(lr[i] - mx) * inv;
}

// ---------------------------------------------------------------------------
extern "C" void kernel_launch(void* const* d_in, const int* in_sizes, int n_in,
                              void* d_out, int out_size, void* d_ws, size_t ws_size,
                              hipStream_t stream) {
  (void)in_sizes; (void)n_in; (void)out_size; (void)ws_size;
  const int* tokens = (const int*)d_in[0];
  const float* emb = (const float*)d_in[1];
  const float* Wq = (const float*)d_in[2];
  const float* Wk = (const float*)d_in[3];
  const float* Wv = (const float*)d_in[4];
  const float* Wo = (const float*)d_in[5];
  const float* lng = (const float*)d_in[6];
  const float* lnb = (const float*)d_in[7];
  const float* w1 = (const float*)d_in[8];
  const float* b1 = (const float*)d_in[9];
  const float* w2 = (const float*)d_in[10];
  const float* b2 = (const float*)d_in[11];
  const float* fnull = nullptr;

  const size_t NA = (size_t)kM * kD;  // 4 MB each
  float* x = (float*)d_ws;
  float* q = x + NA;
  float* k = q + NA;
  float* v = k + NA;
  float* ao = v + NA;
  float* t1 = ao + NA;

  embed_kernel<<<kM, 256, 0, stream>>>(tokens, emb, x);
  for (int l = 0; l < kL; ++l) {
    for (int j = 0; j < 2; ++j) {
      const size_t lj = (size_t)(l * 2 + j);
      mgemm<2, 64, 64, 3, 0, 0><<<dim3(kM / 64, kH, 3), 256, 0, stream>>>(
          x, Wq + lj * kH * kD * kDK, Wk + lj * kH * kD * kDK,
          Wv + lj * kH * kD * kDK, q, k, v, fnull, kM, kDK, kD);
      attn_kernel<<<dim3(kS / 32, kB * kH), 256, 0, stream>>>(q, k, v, ao);
      mgemm<0, 64, 64, 3, 0, 0><<<dim3(kM / 64, kD / 64), 256, 0, stream>>>(
          ao, Wo + lj * kD * kD, fnull, fnull, t1, nullptr, nullptr, fnull,
          kM, kD, kD);
      ln_kernel<<<kM, 256, 0, stream>>>(x, t1, lng + (size_t)(l * 3 + j) * kS * kD,
                                        lnb + (size_t)(l * 3 + j) * kS * kD);
    }
    mgemm<0, 64, 64, 3, 1, 1><<<dim3(kM / 64, kD / 64), 256, 0, stream>>>(
        x, w1 + (size_t)l * kD * kD, fnull, fnull, t1, nullptr, nullptr,
        b1 + (size_t)l * kD, kM, kD, kD);
    mgemm<0, 64, 64, 3, 1, 0><<<dim3(kM / 64, kD / 64), 256, 0, stream>>>(
        t1, w2 + (size_t)l * kD * kD, fnull, fnull, ao, nullptr, nullptr,
        b2 + (size_t)l * kD, kM, kD, kD);
    ln_kernel<<<kM, 256, 0, stream>>>(x, ao, lng + (size_t)(l * 3 + 2) * kS * kD,
                                      lnb + (size_t)(l * 3 + 2) * kS * kD);
  }
  // logits = x @ emb.T (plain bf16 MFMA) -> fp32 in d_out; softmax in place
  float* logits = (float*)d_out;
  mgemm<1, 128, 128, 1, 0, 0><<<dim3(kM / 128, kV / 128), 256, 0, stream>>>(
      x, emb, fnull, fnull, logits, nullptr, nullptr, fnull, kM, kV, kD);
  softmax_kernel<<<kM, 256, 0, stream>>>(logits);
}

// Round 5
// 1087.673 us; speedup vs baseline: 2.7971x; 1.8484x over previous
//
#include <hip/hip_runtime.h>
#include <hip/hip_bf16.h>

typedef __hip_bfloat16 bf16;
typedef unsigned short u16;
typedef short bf16x8 __attribute__((ext_vector_type(8)));
typedef float f32x4 __attribute__((ext_vector_type(4)));
typedef unsigned short u16x4 __attribute__((ext_vector_type(4)));
typedef unsigned short u16x8 __attribute__((ext_vector_type(8)));

constexpr int kB = 2;
constexpr int kS = 1024;
constexpr int kD = 512;
constexpr int kH = 8;
constexpr int kDK = 64;
constexpr int kL = 4;
constexpr int kV = 32000;
constexpr int kM = kB * kS;   // 2048 rows
constexpr int kNB = kV / 128; // vocab n-blocks = 250

__device__ __forceinline__ u16 f2bh(float x) {
  unsigned u = __builtin_bit_cast(unsigned, x);
  unsigned r = u + 0x7fffu + ((u >> 16) & 1u);
  return (u16)(r >> 16);
}
__device__ __forceinline__ float bh2f(u16 h) {
  return __builtin_bit_cast(float, (unsigned)h << 16);
}

// ---------------------------------------------------------------- embed + PE
__global__ __launch_bounds__(256)
void embed_kernel(const int* __restrict__ tokens, const float* __restrict__ emb,
                  float* __restrict__ x) {
  const int row = blockIdx.x;            // b*S + s
  const int s = row & (kS - 1);
  const int tok = tokens[row];
  const float scl = sqrtf((float)kD);    // applied AFTER adding pe (faithful)
  for (int d = threadIdx.x; d < kD; d += 256) {
    float e = emb[(size_t)tok * kD + d];
    float den = powf(10000.0f, 2.0f * (float)d / (float)kD);
    float ang = (float)s / den;
    float pe = ((d & 1) == 0) ? sinf(ang) : cosf(ang);
    x[(size_t)row * kD + d] = (e + pe) * scl;
  }
}

// --------------------------------------------------- MFMA split-bf16 GEMM
// MODE 0: C = A @ B, B fp32 [K][N] row-major.
// MODE 1: C = A @ B^T, B fp32 [N][K] row-major (vocab: emb).
// MODE 2: qkv — blockIdx.y = head, blockIdx.z selects (B0,C0)/(B1,C1)/(B2,C2);
//         B block = W + h*K*64 ([K][64]); out bf16, layout [B,H,S,DK].
// SPLIT: 1 = plain bf16, 3 = hi*hi + lo*hi + hi*lo (near-fp32).
// OBF16: write bf16 output.  SEXP: write exp(c) + per-row-block partial sums.
template <int MODE, int BM, int BN, int SPLIT, int BIAS, int RELU, int OBF16, int SEXP>
__global__ __launch_bounds__(256)
void mgemm(const float* __restrict__ A,
           const float* __restrict__ B0, const float* __restrict__ B1,
           const float* __restrict__ B2,
           void* __restrict__ C0, void* __restrict__ C1, void* __restrict__ C2,
           const float* __restrict__ bias, float* __restrict__ partials,
           int Mdim, int Ndim, int Kdim) {
  constexpr int LDK = 40;            // padded bf16 k-stride (80 B, 16B-aligned)
  constexpr int MF = BM / 32;        // frags per wave (wave grid 2x2)
  constexpr int NF = BN / 32;
  __shared__ __align__(16) u16 Ah[BM * LDK];
  __shared__ __align__(16) u16 Bh[BN * LDK];
  __shared__ __align__(16) u16 Al[(SPLIT > 1 ? BM : 1) * LDK];
  __shared__ __align__(16) u16 Bl[(SPLIT > 1 ? BN : 1) * LDK];
  __shared__ float plds[SEXP ? 2 * BM : 1];

  const int t = threadIdx.x;
  const int lane = t & 63;
  const int g = lane >> 4, li = lane & 15;
  const int w = t >> 6;
  const int wr = w >> 1, wc = w & 1;
  const int m0 = blockIdx.x * BM;
  int n0;
  const float* Bm;
  void* Cc;
  if (MODE == 2) {
    n0 = 0;
    const float* Ws = (blockIdx.z == 0) ? B0 : (blockIdx.z == 1) ? B1 : B2;
    Bm = Ws + (size_t)blockIdx.y * Kdim * 64;
    Cc = (blockIdx.z == 0) ? C0 : (blockIdx.z == 1) ? C1 : C2;
  } else {
    n0 = blockIdx.y * BN;
    Bm = B0;
    Cc = C0;
  }

  f32x4 acc[MF][NF];
#pragma unroll
  for (int i = 0; i < MF; ++i)
#pragma unroll
    for (int j = 0; j < NF; ++j) acc[i][j] = (f32x4){0.f, 0.f, 0.f, 0.f};

  for (int k0 = 0; k0 < Kdim; k0 += 32) {
    __syncthreads();
#pragma unroll
    for (int it = 0; it < BM / 32; ++it) {
      const int idx = it * 256 + t;
      const int row = idx >> 3, c4 = (idx & 7) * 4;
      float4 v = *reinterpret_cast<const float4*>(
          &A[(size_t)(m0 + row) * Kdim + k0 + c4]);
      u16x4 h;
      h[0] = f2bh(v.x); h[1] = f2bh(v.y); h[2] = f2bh(v.z); h[3] = f2bh(v.w);
      *reinterpret_cast<u16x4*>(&Ah[row * LDK + c4]) = h;
      if (SPLIT > 1) {
        u16x4 lo;
        lo[0] = f2bh(v.x - bh2f(h[0])); lo[1] = f2bh(v.y - bh2f(h[1]));
        lo[2] = f2bh(v.z - bh2f(h[2])); lo[3] = f2bh(v.w - bh2f(h[3]));
        *reinterpret_cast<u16x4*>(&Al[row * LDK + c4]) = lo;
      }
    }
    if (MODE == 1) {
#pragma unroll
      for (int it = 0; it < BN / 32; ++it) {
        const int idx = it * 256 + t;
        const int row = idx >> 3, c4 = (idx & 7) * 4;
        float4 v = *reinterpret_cast<const float4*>(
            &B0[(size_t)(n0 + row) * Kdim + k0 + c4]);
        u16x4 h;
        h[0] = f2bh(v.x); h[1] = f2bh(v.y); h[2] = f2bh(v.z); h[3] = f2bh(v.w);
        *reinterpret_cast<u16x4*>(&Bh[row * LDK + c4]) = h;
        if (SPLIT > 1) {
          u16x4 lo;
          lo[0] = f2bh(v.x - bh2f(h[0])); lo[1] = f2bh(v.y - bh2f(h[1]));
          lo[2] = f2bh(v.z - bh2f(h[2])); lo[3] = f2bh(v.w - bh2f(h[3]));
          *reinterpret_cast<u16x4*>(&Bl[row * LDK + c4]) = lo;
        }
      }
    } else {
      constexpr int KPER = 32 * BN / 256;
      const int n = t & (BN - 1);
      const int kb = (t / BN) * KPER;
      float xs[KPER];
#pragma unroll
      for (int i = 0; i < KPER; ++i)
        xs[i] = Bm[(size_t)(k0 + kb + i) * Ndim + n0 + n];
#pragma unroll
      for (int ch = 0; ch < KPER / 8; ++ch) {
        u16x8 h, lo;
#pragma unroll
        for (int i = 0; i < 8; ++i) {
          float xv = xs[ch * 8 + i];
          h[i] = f2bh(xv);
          if (SPLIT > 1) lo[i] = f2bh(xv - bh2f(h[i]));
        }
        *reinterpret_cast<u16x8*>(&Bh[n * LDK + kb + ch * 8]) = h;
        if (SPLIT > 1)
          *reinterpret_cast<u16x8*>(&Bl[n * LDK + kb + ch * 8]) = lo;
      }
    }
    __syncthreads();
    bf16x8 fah[MF], fal[MF], fbh[NF], fbl[NF];
#pragma unroll
    for (int fm = 0; fm < MF; ++fm) {
      const int off = (wr * (BM / 2) + fm * 16 + li) * LDK + g * 8;
      fah[fm] = *reinterpret_cast<const bf16x8*>(&Ah[off]);
      if (SPLIT > 1) fal[fm] = *reinterpret_cast<const bf16x8*>(&Al[off]);
    }
#pragma unroll
    for (int fn = 0; fn < NF; ++fn) {
      const int off = (wc * (BN / 2) + fn * 16 + li) * LDK + g * 8;
      fbh[fn] = *reinterpret_cast<const bf16x8*>(&Bh[off]);
      if (SPLIT > 1) fbl[fn] = *reinterpret_cast<const bf16x8*>(&Bl[off]);
    }
#pragma unroll
    for (int fm = 0; fm < MF; ++fm)
#pragma unroll
      for (int fn = 0; fn < NF; ++fn) {
        acc[fm][fn] = __builtin_amdgcn_mfma_f32_16x16x32_bf16(
            fah[fm], fbh[fn], acc[fm][fn], 0, 0, 0);
        if (SPLIT > 1) {
          acc[fm][fn] = __builtin_amdgcn_mfma_f32_16x16x32_bf16(
              fal[fm], fbh[fn], acc[fm][fn], 0, 0, 0);
          acc[fm][fn] = __builtin_amdgcn_mfma_f32_16x16x32_bf16(
              fah[fm], fbl[fn], acc[fm][fn], 0, 0, 0);
        }
      }
  }
  // ---- epilogue: D col = lane&15, row = (lane>>4)*4 + reg
#pragma unroll
  for (int fm = 0; fm < MF; ++fm)
#pragma unroll
    for (int fn = 0; fn < NF; ++fn)
#pragma unroll
      for (int r = 0; r < 4; ++r) {
        const int m = m0 + wr * (BM / 2) + fm * 16 + g * 4 + r;
        const int n = n0 + wc * (BN / 2) + fn * 16 + li;
        float c = acc[fm][fn][r];
        if (BIAS) c += bias[n];
        if (RELU) c = fmaxf(c, 0.0f);
        if (SEXP) { c = __expf(c); acc[fm][fn][r] = c; }
        size_t idx;
        if (MODE == 2) {
          const int b_ = m >> 10, s = m & (kS - 1);
          idx = ((size_t)(b_ * kH + blockIdx.y) * kS + s) * kDK + n;
        } else {
          idx = (size_t)m * Ndim + n;
        }
        if (OBF16) ((u16*)Cc)[idx] = f2bh(c);
        else ((float*)Cc)[idx] = c;
      }
  if (SEXP) {
    // deterministic per-row partial sums: one slot per (wc, row), 1 writer each
#pragma unroll
    for (int fm = 0; fm < MF; ++fm)
#pragma unroll
      for (int r = 0; r < 4; ++r) {
        float sv = 0.f;
#pragma unroll
        for (int fn = 0; fn < NF; ++fn) sv += acc[fm][fn][r];
        sv += __shfl_xor(sv, 1); sv += __shfl_xor(sv, 2);
        sv += __shfl_xor(sv, 4); sv += __shfl_xor(sv, 8);
        if (li == 0) plds[wc * BM + wr * (BM / 2) + fm * 16 + g * 4 + r] = sv;
      }
    __syncthreads();
    if (t < BM)
      partials[(size_t)(m0 + t) * gridDim.y + blockIdx.y] =
          plds[t] + plds[BM + t];
  }
}

// --------------------------------------------- MFMA flash attention (bf16)
// grid (S/64, B*H), 256 thr (4 waves, 16 q-rows each). q/k/v bf16 [B,H,S,DK].
// out fp32 [B,S,D] head-concat. Non-causal. Scores scaled by 1/8 post-MFMA.
__global__ __launch_bounds__(256)
void attn_kernel(const u16* __restrict__ qg, const u16* __restrict__ kg,
                 const u16* __restrict__ vg, float* __restrict__ out) {
  __shared__ __align__(16) u16 Kt[2][64][40];  // [kiter d/32][kv][d%32]
  __shared__ __align__(16) u16 Vt[2][64][40];  // [kv/32][d][kv%32] oct^=(d>>4)
  __shared__ __align__(16) u16 Pt[2][64][40];  // [kv/32][q][kv%32]
  const int t = threadIdx.x;
  const int lane = t & 63;
  const int g = lane >> 4, li = lane & 15;
  const int w = t >> 6;
  const int bh = blockIdx.y;
  const int q0 = blockIdx.x * 64;
  const size_t base = (size_t)bh * kS * kDK;

  // stage Q tile into Kt, pull per-wave A-frags
  {
    const int r = t >> 2, dq = (t & 3) * 16;
    const u16* src = &qg[base + (size_t)(q0 + r) * kDK + dq];
    u16x8 a = *(const u16x8*)src;
    u16x8 b = *(const u16x8*)(src + 8);
    *(u16x8*)&Kt[dq >> 5][r][dq & 31] = a;
    *(u16x8*)&Kt[dq >> 5][r][(dq & 31) + 8] = b;
  }
  __syncthreads();
  bf16x8 qf0 = *(const bf16x8*)&Kt[0][w * 16 + li][g * 8];
  bf16x8 qf1 = *(const bf16x8*)&Kt[1][w * 16 + li][g * 8];

  float m_[4] = {-1e30f, -1e30f, -1e30f, -1e30f};
  float l_[4] = {0.f, 0.f, 0.f, 0.f};
  f32x4 apv[4];
#pragma unroll
  for (int i = 0; i < 4; ++i) apv[i] = (f32x4){0.f, 0.f, 0.f, 0.f};

  for (int kt = 0; kt < kS / 64; ++kt) {
    __syncthreads();  // previous tile's reads done
    {
      const int r = t >> 2, dq = (t & 3) * 16;
      const u16* ks = &kg[base + (size_t)(kt * 64 + r) * kDK + dq];
      u16x8 a = *(const u16x8*)ks;
      u16x8 b = *(const u16x8*)(ks + 8);
      *(u16x8*)&Kt[dq >> 5][r][dq & 31] = a;
      *(u16x8*)&Kt[dq >> 5][r][(dq & 31) + 8] = b;
      const u16* vs = &vg[base + (size_t)(kt * 64 + r) * kDK + dq];
      u16x8 va = *(const u16x8*)vs;
      u16x8 vb = *(const u16x8*)(vs + 8);
      const int vc = r >> 5, ko = (r & 31) >> 3, kp = r & 7;
#pragma unroll
      for (int i = 0; i < 8; ++i) {
        const int d = dq + i;
        Vt[vc][d][((ko ^ (d >> 4)) << 3) | kp] = va[i];
      }
#pragma unroll
      for (int i = 0; i < 8; ++i) {
        const int d = dq + 8 + i;
        Vt[vc][d][((ko ^ (d >> 4)) << 3) | kp] = vb[i];
      }
    }
    __syncthreads();
    // QK^T: s frag nf covers kv = nf*16+li
    f32x4 s[4];
#pragma unroll
    for (int nf = 0; nf < 4; ++nf) {
      bf16x8 k0 = *(const bf16x8*)&Kt[0][nf * 16 + li][g * 8];
      bf16x8 k1 = *(const bf16x8*)&Kt[1][nf * 16 + li][g * 8];
      f32x4 sa = (f32x4){0.f, 0.f, 0.f, 0.f};
      sa = __builtin_amdgcn_mfma_f32_16x16x32_bf16(qf0, k0, sa, 0, 0, 0);
      sa = __builtin_amdgcn_mfma_f32_16x16x32_bf16(qf1, k1, sa, 0, 0, 0);
      s[nf] = sa;
    }
    // online softmax (rows = g*4+r, shared across li lanes)
    float corr[4];
#pragma unroll
    for (int r = 0; r < 4; ++r) {
      float tm = fmaxf(fmaxf(s[0][r], s[1][r]), fmaxf(s[2][r], s[3][r])) * 0.125f;
      tm = fmaxf(tm, __shfl_xor(tm, 1));
      tm = fmaxf(tm, __shfl_xor(tm, 2));
      tm = fmaxf(tm, __shfl_xor(tm, 4));
      tm = fmaxf(tm, __shfl_xor(tm, 8));
      const float nm = fmaxf(m_[r], tm);
      corr[r] = __expf(m_[r] - nm);
      m_[r] = nm;
    }
    float tsum[4] = {0.f, 0.f, 0.f, 0.f};
    u16 pb[4][4];
#pragma unroll
    for (int nf = 0; nf < 4; ++nf)
#pragma unroll
      for (int r = 0; r < 4; ++r) {
        float p = __expf(s[nf][r] * 0.125f - m_[r]);
        tsum[r] += p;
        pb[nf][r] = f2bh(p);
      }
#pragma unroll
    for (int r = 0; r < 4; ++r) {
      float ts = tsum[r];
      ts += __shfl_xor(ts, 1); ts += __shfl_xor(ts, 2);
      ts += __shfl_xor(ts, 4); ts += __shfl_xor(ts, 8);
      l_[r] = l_[r] * corr[r] + ts;
#pragma unroll
      for (int nf = 0; nf < 4; ++nf) apv[nf][r] *= corr[r];
    }
    // write P (bf16) to wave-local rows; no barrier needed (same-wave reuse)
#pragma unroll
    for (int nf = 0; nf < 4; ++nf)
#pragma unroll
      for (int r = 0; r < 4; ++r)
        Pt[nf >> 1][w * 16 + g * 4 + r][(nf & 1) * 16 + li] = pb[nf][r];
    // PV: A = P[q][kv], B = Vt[d][kv]
    bf16x8 p0 = *(const bf16x8*)&Pt[0][w * 16 + li][g * 8];
    bf16x8 p1 = *(const bf16x8*)&Pt[1][w * 16 + li][g * 8];
#pragma unroll
    for (int nf = 0; nf < 4; ++nf) {
      bf16x8 v0 = *(const bf16x8*)&Vt[0][nf * 16 + li][((g ^ nf) & 3) * 8];
      bf16x8 v1 = *(const bf16x8*)&Vt[1][nf * 16 + li][((g ^ nf) & 3) * 8];
      apv[nf] = __builtin_amdgcn_mfma_f32_16x16x32_bf16(p0, v0, apv[nf], 0, 0, 0);
      apv[nf] = __builtin_amdgcn_mfma_f32_16x16x32_bf16(p1, v1, apv[nf], 0, 0, 0);
    }
  }
  const int b_ = bh >> 3, h_ = bh & 7;
#pragma unroll
  for (int r = 0; r < 4; ++r) {
    const float inv = 1.0f / l_[r];
    const int row = q0 + w * 16 + g * 4 + r;
#pragma unroll
    for (int nf = 0; nf < 4; ++nf)
      out[((size_t)(b_ * kS + row)) * kD + h_ * kDK + nf * 16 + li] =
          apv[nf][r] * inv;
  }
}

// --------------------------------------------- residual + LayerNorm in place
__global__ __launch_bounds__(256)
void ln_kernel(float* __restrict__ x, const float* __restrict__ h,
               const float* __restrict__ gain, const float* __restrict__ bias) {
  const int row = blockIdx.x;
  const int s = row & (kS - 1);
  const int t = threadIdx.x;
  float* xr = x + (size_t)row * kD;
  const float* hr = h + (size_t)row * kD;
  const float v0 = xr[t] + hr[t];
  const float v1 = xr[t + 256] + hr[t + 256];
  float sum = v0 + v1;
  float sq = v0 * v0 + v1 * v1;
#pragma unroll
  for (int off = 1; off < 64; off <<= 1) {
    sum += __shfl_xor(sum, off);
    sq += __shfl_xor(sq, off);
  }
  __shared__ float rs[4], rq[4];
  if ((t & 63) == 0) { rs[t >> 6] = sum; rq[t >> 6] = sq; }
  __syncthreads();
  sum = rs[0] + rs[1] + rs[2] + rs[3];
  sq = rq[0] + rq[1] + rq[2] + rq[3];
  const float mean = sum * (1.0f / kD);
  const float var = fmaxf(sq * (1.0f / kD) - mean * mean, 0.0f);
  const float inv = 1.0f / (sqrtf(var) + 1e-6f);
  const float* gr = gain + (size_t)s * kD;
  const float* br = bias + (size_t)s * kD;
  xr[t] = gr[t] * inv * (v0 - mean) + br[t];
  xr[t + 256] = gr[t + 256] * inv * (v1 - mean) + br[t + 256];
}

// -------------------------------------------- softmax tail: rowsum + scale
__global__ __launch_bounds__(256)
void rowsum_kernel(const float* __restrict__ partials, float* __restrict__ rowinv) {
  const int row = blockIdx.x;
  const int t = threadIdx.x;
  float s = (t < kNB) ? partials[(size_t)row * kNB + t] : 0.f;
#pragma unroll
  for (int off = 1; off < 64; off <<= 1) s += __shfl_xor(s, off);
  __shared__ float red[4];
  if ((t & 63) == 0) red[t >> 6] = s;
  __syncthreads();
  if (t == 0) rowinv[row] = 1.0f / (red[0] + red[1] + red[2] + red[3]);
}

__global__ __launch_bounds__(256)
void scale_kernel(float* __restrict__ lg, const float* __restrict__ rowinv) {
  const int row = blockIdx.x;
  const float inv = rowinv[row];
  float4* p = (float4*)(lg + (size_t)row * kV);
  for (int i = threadIdx.x; i < kV / 4; i += 256) {
    float4 v = p[i];
    v.x *= inv; v.y *= inv; v.z *= inv; v.w *= inv;
    p[i] = v;
  }
}

// ---------------------------------------------------------------------------
extern "C" void kernel_launch(void* const* d_in, const int* in_sizes, int n_in,
                              void* d_out, int out_size, void* d_ws, size_t ws_size,
                              hipStream_t stream) {
  (void)in_sizes; (void)n_in; (void)out_size; (void)ws_size;
  const int* tokens = (const int*)d_in[0];
  const float* emb = (const float*)d_in[1];
  const float* Wq = (const float*)d_in[2];
  const float* Wk = (const float*)d_in[3];
  const float* Wv = (const float*)d_in[4];
  const float* Wo = (const float*)d_in[5];
  const float* lng = (const float*)d_in[6];
  const float* lnb = (const float*)d_in[7];
  const float* w1 = (const float*)d_in[8];
  const float* b1 = (const float*)d_in[9];
  const float* w2 = (const float*)d_in[10];
  const float* b2 = (const float*)d_in[11];
  const float* fnull = nullptr;

  const size_t NA = (size_t)kM * kD;  // 1M elements
  float* x = (float*)d_ws;            // 4 MB
  u16* qb = (u16*)(x + NA);           // 2 MB
  u16* kb = qb + NA;                  // 2 MB
  u16* vb = kb + NA;                  // 2 MB
  float* ao = (float*)(vb + NA);      // 4 MB
  float* t1 = ao + NA;                // 4 MB
  float* partials = t1 + NA;          // 2048*250*4 = 2 MB
  float* rowinv = partials + (size_t)kM * kNB;  // 8 KB

  embed_kernel<<<kM, 256, 0, stream>>>(tokens, emb, x);
  for (int l = 0; l < kL; ++l) {
    for (int j = 0; j < 2; ++j) {
      const size_t lj = (size_t)(l * 2 + j);
      mgemm<2, 64, 64, 3, 0, 0, 1, 0><<<dim3(kM / 64, kH, 3), 256, 0, stream>>>(
          x, Wq + lj * kH * kD * kDK, Wk + lj * kH * kD * kDK,
          Wv + lj * kH * kD * kDK, qb, kb, vb, fnull, nullptr, kM, kDK, kD);
      attn_kernel<<<dim3(kS / 64, kB * kH), 256, 0, stream>>>(qb, kb, vb, ao);
      mgemm<0, 64, 64, 3, 0, 0, 0, 0><<<dim3(kM / 64, kD / 64), 256, 0, stream>>>(
          ao, Wo + lj * kD * kD, fnull, fnull, t1, nullptr, nullptr, fnull,
          nullptr, kM, kD, kD);
      ln_kernel<<<kM, 256, 0, stream>>>(x, t1, lng + (size_t)(l * 3 + j) * kS * kD,
                                        lnb + (size_t)(l * 3 + j) * kS * kD);
    }
    mgemm<0, 64, 64, 3, 1, 1, 0, 0><<<dim3(kM / 64, kD / 64), 256, 0, stream>>>(
        x, w1 + (size_t)l * kD * kD, fnull, fnull, t1, nullptr, nullptr,
        b1 + (size_t)l * kD, nullptr, kM, kD, kD);
    mgemm<0, 64, 64, 3, 1, 0, 0, 0><<<dim3(kM / 64, kD / 64), 256, 0, stream>>>(
        t1, w2 + (size_t)l * kD * kD, fnull, fnull, ao, nullptr, nullptr,
        b2 + (size_t)l * kD, nullptr, kM, kD, kD);
    ln_kernel<<<kM, 256, 0, stream>>>(x, ao, lng + (size_t)(l * 3 + 2) * kS * kD,
                                      lnb + (size_t)(l * 3 + 2) * kS * kD);
  }
  // logits: e = exp(x @ emb.T) -> d_out (fp32) + deterministic partial sums
  float* logits = (float*)d_out;
  mgemm<1, 128, 128, 1, 0, 0, 0, 1><<<dim3(kM / 128, kNB), 256, 0, stream>>>(
      x, emb, fnull, fnull, logits, nullptr, nullptr, fnull, partials,
      kM, kV, kD);
  rowsum_kernel<<<kM, 256, 0, stream>>>(partials, rowinv);
  scale_kernel<<<kM, 256, 0, stream>>>(logits, rowinv);
}

// Round 6
// 865.599 us; speedup vs baseline: 3.5147x; 1.2566x over previous
//
#include <hip/hip_runtime.h>
#include <hip/hip_bf16.h>

typedef unsigned short u16;
typedef short bf16x8 __attribute__((ext_vector_type(8)));
typedef float f32x4 __attribute__((ext_vector_type(4)));
typedef unsigned short u16x8 __attribute__((ext_vector_type(8)));

constexpr int kB = 2;
constexpr int kS = 1024;
constexpr int kD = 512;
constexpr int kH = 8;
constexpr int kDK = 64;
constexpr int kL = 4;
constexpr int kV = 32000;
constexpr int kM = kB * kS;   // 2048
constexpr int kNB = kV / 128; // 250

__device__ __forceinline__ u16 f2bh(float x) {
  unsigned u = __builtin_bit_cast(unsigned, x);
  unsigned r = u + 0x7fffu + ((u >> 16) & 1u);
  return (u16)(r >> 16);
}
__device__ __forceinline__ float bh2f(u16 h) {
  return __builtin_bit_cast(float, (unsigned)h << 16);
}
// swizzled u16 index for element (row, k) in a [*][512] bf16 array:
// 16B-block (k>>3)&7 is XORed with row&7 within each 64-k chunk.
__device__ __forceinline__ size_t swz_idx(int row, int k) {
  return (size_t)row * kD + (k & ~63) + ((((k >> 3) & 7) ^ (row & 7)) << 3) + (k & 7);
}

// ------------------------------------------- weight conversion (transpose)
// Wq/Wk/Wv (L*2, H, D, DK) fp32 -> wqkv[lj][mat*512 + h*64 + dk][k] bf16 hi/lo,
// swizzled per (dk-row & 7).
__global__ __launch_bounds__(256)
void conv_qkv(const float* __restrict__ Wq, const float* __restrict__ Wk,
              const float* __restrict__ Wv, u16* __restrict__ oh, u16* __restrict__ ol) {
  __shared__ float ld[64][65];
  const int kc = blockIdx.x, h = blockIdx.y, z = blockIdx.z;
  const int mat = z >> 3, lj = z & 7;
  const float* src = (mat == 0 ? Wq : mat == 1 ? Wk : Wv) +
                     ((size_t)(lj * kH + h)) * kD * kDK + (size_t)kc * 64 * kDK;
  const int t = threadIdx.x;
#pragma unroll
  for (int i = 0; i < 16; ++i) {
    const int idx = i * 256 + t;
    ld[idx >> 6][idx & 63] = src[idx];
  }
  __syncthreads();
  const int dkr = t >> 2, jb = t & 3;
  const size_t rowbase = ((size_t)lj * 1536 + mat * kD + h * kDK + dkr) * kD + kc * 64;
#pragma unroll
  for (int q = 0; q < 2; ++q) {
    const int jj = jb + q * 4;
    const int jsw = jj ^ (dkr & 7);
    u16x8 hi, lo;
#pragma unroll
    for (int e = 0; e < 8; ++e) {
      float v = ld[jj * 8 + e][dkr];
      hi[e] = f2bh(v);
      lo[e] = f2bh(v - bh2f(hi[e]));
    }
    *(u16x8*)&oh[rowbase + jsw * 8] = hi;
    *(u16x8*)&ol[rowbase + jsw * 8] = lo;
  }
}

// Wo (8x[512][512]), w1 (4x), w2 (4x) fp32 -> [mat][N][K] bf16 hi/lo swizzled.
__global__ __launch_bounds__(256)
void conv_sq(const float* __restrict__ Wo, const float* __restrict__ w1,
             const float* __restrict__ w2, u16* __restrict__ woh, u16* __restrict__ wol,
             u16* __restrict__ w1h, u16* __restrict__ w1l,
             u16* __restrict__ w2h, u16* __restrict__ w2l) {
  __shared__ float ld[64][65];
  const int kc = blockIdx.x, nc = blockIdx.y, mid = blockIdx.z;
  const float* src;
  u16 *dh, *dl;
  if (mid < 8) { src = Wo + (size_t)mid * kD * kD; dh = woh + (size_t)mid * kD * kD; dl = wol + (size_t)mid * kD * kD; }
  else if (mid < 12) { int l = mid - 8; src = w1 + (size_t)l * kD * kD; dh = w1h + (size_t)l * kD * kD; dl = w1l + (size_t)l * kD * kD; }
  else { int l = mid - 12; src = w2 + (size_t)l * kD * kD; dh = w2h + (size_t)l * kD * kD; dl = w2l + (size_t)l * kD * kD; }
  const int t = threadIdx.x;
#pragma unroll
  for (int i = 0; i < 16; ++i) {
    const int idx = i * 256 + t;
    const int kl = idx >> 6, nl = idx & 63;
    ld[kl][nl] = src[(size_t)(kc * 64 + kl) * kD + nc * 64 + nl];
  }
  __syncthreads();
  const int nr = t >> 2, jb = t & 3;
  const size_t rowbase = (size_t)(nc * 64 + nr) * kD + kc * 64;
#pragma unroll
  for (int q = 0; q < 2; ++q) {
    const int jj = jb + q * 4;
    const int jsw = jj ^ (nr & 7);
    u16x8 hi, lo;
#pragma unroll
    for (int e = 0; e < 8; ++e) {
      float v = ld[jj * 8 + e][nr];
      hi[e] = f2bh(v);
      lo[e] = f2bh(v - bh2f(hi[e]));
    }
    *(u16x8*)&dh[rowbase + jsw * 8] = hi;
    *(u16x8*)&dl[rowbase + jsw * 8] = lo;
  }
}

// emb (V, D) fp32 -> [V][K] bf16 hi-only, swizzled.
__global__ __launch_bounds__(256)
void conv_emb(const float* __restrict__ emb, u16* __restrict__ oh) {
  const int chunk = blockIdx.x * 256 + threadIdx.x;  // 2,048,000 chunks
  const int n = chunk >> 6, j = chunk & 63;
  const float* s = &emb[(size_t)n * kD + j * 8];
  float4 a = *(const float4*)s, b = *(const float4*)(s + 4);
  u16x8 hi;
  hi[0] = f2bh(a.x); hi[1] = f2bh(a.y); hi[2] = f2bh(a.z); hi[3] = f2bh(a.w);
  hi[4] = f2bh(b.x); hi[5] = f2bh(b.y); hi[6] = f2bh(b.z); hi[7] = f2bh(b.w);
  *(u16x8*)&oh[(size_t)n * kD + (j & ~7) * 8 + (((j & 7) ^ (n & 7)) << 3)] = hi;
}

// ---------------------------------------------------------------- embed + PE
__global__ __launch_bounds__(256)
void embed_kernel(const int* __restrict__ tokens, const float* __restrict__ emb,
                  float* __restrict__ x, u16* __restrict__ xh, u16* __restrict__ xl) {
  const int row = blockIdx.x;
  const int s = row & (kS - 1);
  const int tok = tokens[row];
  const float scl = sqrtf((float)kD);
  for (int d = threadIdx.x; d < kD; d += 256) {
    float e = emb[(size_t)tok * kD + d];
    float den = powf(10000.0f, 2.0f * (float)d / (float)kD);
    float ang = (float)s / den;
    float pe = ((d & 1) == 0) ? sinf(ang) : cosf(ang);
    float o = (e + pe) * scl;
    x[(size_t)row * kD + d] = o;
    u16 hi = f2bh(o);
    size_t p = swz_idx(row, d);
    xh[p] = hi;
    xl[p] = f2bh(o - bh2f(hi));
  }
}

// --------------------------------------------------- MFMA GEMM, bf16 inputs
// C = A @ B^T. A: [M][K] bf16 (hi[,lo]) swizzled. B: [N][K] bf16 swizzled.
// OUT: 0 fp32 [M][Nd]; 1 bf16 hi/lo swizzled [M][512]; 2 qkv bf16 scatter;
//      3 exp(c) fp32 + deterministic per-row partials.
template <int SPLIT, int BM, int BN, int OUT, int BIAS, int RELU>
__global__ __launch_bounds__(256)
void mgemm2(const u16* __restrict__ Ah, const u16* __restrict__ Al,
            const u16* __restrict__ Bh, const u16* __restrict__ Bl,
            float* __restrict__ Cf, u16* __restrict__ Ch, u16* __restrict__ Cl,
            const float* __restrict__ bias, float* __restrict__ partials,
            int Kd, int Nd) {
  static_assert(BM == BN, "");
  constexpr int MF = BM / 32, NF = BN / 32;
  constexpr int TA = BM * 64;  // u16 per tile
  __shared__ __align__(16) u16 lds[(SPLIT == 3 ? 4 : 2) * TA];
  __shared__ float plds[OUT == 3 ? 2 * BM : 1];
  const int t = threadIdx.x;
  const int lane = t & 63, g = lane >> 4, li = lane & 15;
  const int w = t >> 6, wr = w >> 1, wc = w & 1;
  const int m0 = blockIdx.x * BM, n0 = blockIdx.y * BN;

  f32x4 acc[MF][NF];
#pragma unroll
  for (int i = 0; i < MF; ++i)
#pragma unroll
    for (int j = 0; j < NF; ++j) acc[i][j] = (f32x4){0.f, 0.f, 0.f, 0.f};

  for (int k0 = 0; k0 < Kd; k0 += 64) {
    __syncthreads();
    // stage tiles: [rows][64k] bf16, linear copy of pre-swizzled global
#pragma unroll
    for (int it = 0; it < BM / 32; ++it) {
      const int idx = it * 256 + t;
      const int r = idx >> 3, j = idx & 7;
      *(u16x8*)&lds[r * 64 + j * 8] =
          *(const u16x8*)&Ah[(size_t)(m0 + r) * Kd + k0 + j * 8];
      if (SPLIT == 3)
        *(u16x8*)&lds[TA + r * 64 + j * 8] =
            *(const u16x8*)&Al[(size_t)(m0 + r) * Kd + k0 + j * 8];
      *(u16x8*)&lds[(SPLIT == 3 ? 2 : 1) * TA + r * 64 + j * 8] =
          *(const u16x8*)&Bh[(size_t)(n0 + r) * Kd + k0 + j * 8];
      if (SPLIT == 3)
        *(u16x8*)&lds[3 * TA + r * 64 + j * 8] =
            *(const u16x8*)&Bl[(size_t)(n0 + r) * Kd + k0 + j * 8];
    }
    __syncthreads();
#pragma unroll
    for (int s = 0; s < 2; ++s) {
      const int s4g = s * 4 + g;
      bf16x8 fah[MF], fbh[NF], fal[SPLIT == 3 ? MF : 1], fbl[SPLIT == 3 ? NF : 1];
#pragma unroll
      for (int fm = 0; fm < MF; ++fm) {
        const int row = wr * (BM / 2) + fm * 16 + li;
        const int off = row * 64 + ((s4g ^ (row & 7)) << 3);
        fah[fm] = *(const bf16x8*)&lds[off];
        if (SPLIT == 3) fal[fm] = *(const bf16x8*)&lds[TA + off];
      }
#pragma unroll
      for (int fn = 0; fn < NF; ++fn) {
        const int row = wc * (BN / 2) + fn * 16 + li;
        const int off = row * 64 + ((s4g ^ (row & 7)) << 3);
        fbh[fn] = *(const bf16x8*)&lds[(SPLIT == 3 ? 2 : 1) * TA + off];
        if (SPLIT == 3) fbl[fn] = *(const bf16x8*)&lds[3 * TA + off];
      }
#pragma unroll
      for (int fm = 0; fm < MF; ++fm)
#pragma unroll
        for (int fn = 0; fn < NF; ++fn) {
          acc[fm][fn] = __builtin_amdgcn_mfma_f32_16x16x32_bf16(
              fah[fm], fbh[fn], acc[fm][fn], 0, 0, 0);
          if (SPLIT == 3) {
            acc[fm][fn] = __builtin_amdgcn_mfma_f32_16x16x32_bf16(
                fal[fm], fbh[fn], acc[fm][fn], 0, 0, 0);
            acc[fm][fn] = __builtin_amdgcn_mfma_f32_16x16x32_bf16(
                fah[fm], fbl[fn], acc[fm][fn], 0, 0, 0);
          }
        }
    }
  }
  // epilogue: D col = lane&15, row = (lane>>4)*4 + reg
#pragma unroll
  for (int fm = 0; fm < MF; ++fm)
#pragma unroll
    for (int fn = 0; fn < NF; ++fn)
#pragma unroll
      for (int r = 0; r < 4; ++r) {
        const int m = m0 + wr * (BM / 2) + fm * 16 + g * 4 + r;
        const int n = n0 + wc * (BN / 2) + fn * 16 + li;
        float c = acc[fm][fn][r];
        if (BIAS) c += bias[n];
        if (RELU) c = fmaxf(c, 0.0f);
        if (OUT == 0) {
          Cf[(size_t)m * Nd + n] = c;
        } else if (OUT == 1) {
          u16 hi = f2bh(c);
          size_t p = swz_idx(m, n);
          Ch[p] = hi;
          Cl[p] = f2bh(c - bh2f(hi));
        } else if (OUT == 2) {
          const int mat = n >> 9, h = (n >> 6) & 7, dk = n & 63;
          const int b_ = m >> 10, s_ = m & (kS - 1);
          Ch[(size_t)mat * (kM * kD / 2) * 2 +
             (((size_t)(b_ * kH + h) * kS + s_) * kDK + dk)] = f2bh(c);
        } else {
          c = __expf(c);
          acc[fm][fn][r] = c;
          Cf[(size_t)m * Nd + n] = c;
        }
      }
  if (OUT == 3) {
#pragma unroll
    for (int fm = 0; fm < MF; ++fm)
#pragma unroll
      for (int r = 0; r < 4; ++r) {
        float sv = 0.f;
#pragma unroll
        for (int fn = 0; fn < NF; ++fn) sv += acc[fm][fn][r];
        sv += __shfl_xor(sv, 1); sv += __shfl_xor(sv, 2);
        sv += __shfl_xor(sv, 4); sv += __shfl_xor(sv, 8);
        if (li == 0) plds[wc * BM + wr * (BM / 2) + fm * 16 + g * 4 + r] = sv;
      }
    __syncthreads();
    if (t < BM)
      partials[(size_t)(m0 + t) * gridDim.y + blockIdx.y] = plds[t] + plds[BM + t];
  }
}

// --------------------------------------------- MFMA flash attention (bf16)
__global__ __launch_bounds__(256)
void attn_kernel(const u16* __restrict__ qg, const u16* __restrict__ kg,
                 const u16* __restrict__ vg, u16* __restrict__ aoh,
                 u16* __restrict__ aol) {
  __shared__ __align__(16) u16 Kt[2][64][40];
  __shared__ __align__(16) u16 Vt[2][64][40];
  __shared__ __align__(16) u16 Pt[2][64][40];
  const int t = threadIdx.x;
  const int lane = t & 63;
  const int g = lane >> 4, li = lane & 15;
  const int w = t >> 6;
  const int bh = blockIdx.y;
  const int q0 = blockIdx.x * 64;
  const size_t base = (size_t)bh * kS * kDK;
  {
    const int r = t >> 2, dq = (t & 3) * 16;
    const u16* src = &qg[base + (size_t)(q0 + r) * kDK + dq];
    u16x8 a = *(const u16x8*)src;
    u16x8 b = *(const u16x8*)(src + 8);
    *(u16x8*)&Kt[dq >> 5][r][dq & 31] = a;
    *(u16x8*)&Kt[dq >> 5][r][(dq & 31) + 8] = b;
  }
  __syncthreads();
  bf16x8 qf0 = *(const bf16x8*)&Kt[0][w * 16 + li][g * 8];
  bf16x8 qf1 = *(const bf16x8*)&Kt[1][w * 16 + li][g * 8];

  float m_[4] = {-1e30f, -1e30f, -1e30f, -1e30f};
  float l_[4] = {0.f, 0.f, 0.f, 0.f};
  f32x4 apv[4];
#pragma unroll
  for (int i = 0; i < 4; ++i) apv[i] = (f32x4){0.f, 0.f, 0.f, 0.f};

  for (int kt = 0; kt < kS / 64; ++kt) {
    __syncthreads();
    {
      const int r = t >> 2, dq = (t & 3) * 16;
      const u16* ks = &kg[base + (size_t)(kt * 64 + r) * kDK + dq];
      u16x8 a = *(const u16x8*)ks;
      u16x8 b = *(const u16x8*)(ks + 8);
      *(u16x8*)&Kt[dq >> 5][r][dq & 31] = a;
      *(u16x8*)&Kt[dq >> 5][r][(dq & 31) + 8] = b;
      const u16* vs = &vg[base + (size_t)(kt * 64 + r) * kDK + dq];
      u16x8 va = *(const u16x8*)vs;
      u16x8 vb = *(const u16x8*)(vs + 8);
      const int vc = r >> 5, ko = (r & 31) >> 3, kp = r & 7;
#pragma unroll
      for (int i = 0; i < 8; ++i) {
        const int d = dq + i;
        Vt[vc][d][((ko ^ (d >> 4)) << 3) | kp] = va[i];
      }
#pragma unroll
      for (int i = 0; i < 8; ++i) {
        const int d = dq + 8 + i;
        Vt[vc][d][((ko ^ (d >> 4)) << 3) | kp] = vb[i];
      }
    }
    __syncthreads();
    f32x4 s[4];
#pragma unroll
    for (int nf = 0; nf < 4; ++nf) {
      bf16x8 k0 = *(const bf16x8*)&Kt[0][nf * 16 + li][g * 8];
      bf16x8 k1 = *(const bf16x8*)&Kt[1][nf * 16 + li][g * 8];
      f32x4 sa = (f32x4){0.f, 0.f, 0.f, 0.f};
      sa = __builtin_amdgcn_mfma_f32_16x16x32_bf16(qf0, k0, sa, 0, 0, 0);
      sa = __builtin_amdgcn_mfma_f32_16x16x32_bf16(qf1, k1, sa, 0, 0, 0);
      s[nf] = sa;
    }
    float corr[4];
#pragma unroll
    for (int r = 0; r < 4; ++r) {
      float tm = fmaxf(fmaxf(s[0][r], s[1][r]), fmaxf(s[2][r], s[3][r])) * 0.125f;
      tm = fmaxf(tm, __shfl_xor(tm, 1));
      tm = fmaxf(tm, __shfl_xor(tm, 2));
      tm = fmaxf(tm, __shfl_xor(tm, 4));
      tm = fmaxf(tm, __shfl_xor(tm, 8));
      const float nm = fmaxf(m_[r], tm);
      corr[r] = __expf(m_[r] - nm);
      m_[r] = nm;
    }
    float tsum[4] = {0.f, 0.f, 0.f, 0.f};
    u16 pb[4][4];
#pragma unroll
    for (int nf = 0; nf < 4; ++nf)
#pragma unroll
      for (int r = 0; r < 4; ++r) {
        float p = __expf(s[nf][r] * 0.125f - m_[r]);
        tsum[r] += p;
        pb[nf][r] = f2bh(p);
      }
#pragma unroll
    for (int r = 0; r < 4; ++r) {
      float ts = tsum[r];
      ts += __shfl_xor(ts, 1); ts += __shfl_xor(ts, 2);
      ts += __shfl_xor(ts, 4); ts += __shfl_xor(ts, 8);
      l_[r] = l_[r] * corr[r] + ts;
#pragma unroll
      for (int nf = 0; nf < 4; ++nf) apv[nf][r] *= corr[r];
    }
#pragma unroll
    for (int nf = 0; nf < 4; ++nf)
#pragma unroll
      for (int r = 0; r < 4; ++r)
        Pt[nf >> 1][w * 16 + g * 4 + r][(nf & 1) * 16 + li] = pb[nf][r];
    bf16x8 p0 = *(const bf16x8*)&Pt[0][w * 16 + li][g * 8];
    bf16x8 p1 = *(const bf16x8*)&Pt[1][w * 16 + li][g * 8];
#pragma unroll
    for (int nf = 0; nf < 4; ++nf) {
      bf16x8 v0 = *(const bf16x8*)&Vt[0][nf * 16 + li][((g ^ nf) & 3) * 8];
      bf16x8 v1 = *(const bf16x8*)&Vt[1][nf * 16 + li][((g ^ nf) & 3) * 8];
      apv[nf] = __builtin_amdgcn_mfma_f32_16x16x32_bf16(p0, v0, apv[nf], 0, 0, 0);
      apv[nf] = __builtin_amdgcn_mfma_f32_16x16x32_bf16(p1, v1, apv[nf], 0, 0, 0);
    }
  }
  const int b_ = bh >> 3, h_ = bh & 7;
#pragma unroll
  for (int r = 0; r < 4; ++r) {
    const float inv = 1.0f / l_[r];
    const int row = q0 + w * 16 + g * 4 + r;
    const int m = b_ * kS + row;
#pragma unroll
    for (int nf = 0; nf < 4; ++nf) {
      const int d = h_ * kDK + nf * 16 + li;
      float o = apv[nf][r] * inv;
      u16 hi = f2bh(o);
      size_t p = swz_idx(m, d);
      aoh[p] = hi;
      aol[p] = f2bh(o - bh2f(hi));
    }
  }
}

// --------------------------------------------- residual + LayerNorm in place
__global__ __launch_bounds__(256)
void ln_kernel(float* __restrict__ x, const float* __restrict__ h,
               const float* __restrict__ gain, const float* __restrict__ bias,
               u16* __restrict__ xh, u16* __restrict__ xl) {
  const int row = blockIdx.x;
  const int s = row & (kS - 1);
  const int t = threadIdx.x;
  float* xr = x + (size_t)row * kD;
  const float* hr = h + (size_t)row * kD;
  const float v0 = xr[t] + hr[t];
  const float v1 = xr[t + 256] + hr[t + 256];
  float sum = v0 + v1;
  float sq = v0 * v0 + v1 * v1;
#pragma unroll
  for (int off = 1; off < 64; off <<= 1) {
    sum += __shfl_xor(sum, off);
    sq += __shfl_xor(sq, off);
  }
  __shared__ float rs[4], rq[4];
  if ((t & 63) == 0) { rs[t >> 6] = sum; rq[t >> 6] = sq; }
  __syncthreads();
  sum = rs[0] + rs[1] + rs[2] + rs[3];
  sq = rq[0] + rq[1] + rq[2] + rq[3];
  const float mean = sum * (1.0f / kD);
  const float var = fmaxf(sq * (1.0f / kD) - mean * mean, 0.0f);
  const float inv = 1.0f / (sqrtf(var) + 1e-6f);
  const float* gr = gain + (size_t)s * kD;
  const float* br = bias + (size_t)s * kD;
  const float o0 = gr[t] * inv * (v0 - mean) + br[t];
  const float o1 = gr[t + 256] * inv * (v1 - mean) + br[t + 256];
  xr[t] = o0;
  xr[t + 256] = o1;
  {
    u16 hi = f2bh(o0);
    size_t p = swz_idx(row, t);
    xh[p] = hi; xl[p] = f2bh(o0 - bh2f(hi));
  }
  {
    u16 hi = f2bh(o1);
    size_t p = swz_idx(row, t + 256);
    xh[p] = hi; xl[p] = f2bh(o1 - bh2f(hi));
  }
}

// -------------------------------------------- softmax tail: rowsum + scale
__global__ __launch_bounds__(256)
void rowsum_kernel(const float* __restrict__ partials, float* __restrict__ rowinv) {
  const int row = blockIdx.x;
  const int t = threadIdx.x;
  float s = (t < kNB) ? partials[(size_t)row * kNB + t] : 0.f;
#pragma unroll
  for (int off = 1; off < 64; off <<= 1) s += __shfl_xor(s, off);
  __shared__ float red[4];
  if ((t & 63) == 0) red[t >> 6] = s;
  __syncthreads();
  if (t == 0) rowinv[row] = 1.0f / (red[0] + red[1] + red[2] + red[3]);
}

__global__ __launch_bounds__(256)
void scale_kernel(float* __restrict__ lg, const float* __restrict__ rowinv) {
  const int row = blockIdx.x;
  const float inv = rowinv[row];
  float4* p = (float4*)(lg + (size_t)row * kV);
  for (int i = threadIdx.x; i < kV / 4; i += 256) {
    float4 v = p[i];
    v.x *= inv; v.y *= inv; v.z *= inv; v.w *= inv;
    p[i] = v;
  }
}

// ---------------------------------------------------------------------------
extern "C" void kernel_launch(void* const* d_in, const int* in_sizes, int n_in,
                              void* d_out, int out_size, void* d_ws, size_t ws_size,
                              hipStream_t stream) {
  (void)in_sizes; (void)n_in; (void)out_size; (void)ws_size;
  const int* tokens = (const int*)d_in[0];
  const float* emb = (const float*)d_in[1];
  const float* Wq = (const float*)d_in[2];
  const float* Wk = (const float*)d_in[3];
  const float* Wv = (const float*)d_in[4];
  const float* Wo = (const float*)d_in[5];
  const float* lng = (const float*)d_in[6];
  const float* lnb = (const float*)d_in[7];
  const float* w1 = (const float*)d_in[8];
  const float* b1 = (const float*)d_in[9];
  const float* w2 = (const float*)d_in[10];
  const float* b2 = (const float*)d_in[11];

  size_t off = 0;
  auto alloc = [&](size_t bytes) {
    void* p = (char*)d_ws + off;
    off += (bytes + 255) & ~(size_t)255;
    return p;
  };
  const size_t NA = (size_t)kM * kD;
  float* x = (float*)alloc(NA * 4);
  u16* xh = (u16*)alloc(NA * 2);
  u16* xl = (u16*)alloc(NA * 2);
  u16* qkvb = (u16*)alloc(3 * NA * 2);
  u16* aoh = (u16*)alloc(NA * 2);
  u16* aol = (u16*)alloc(NA * 2);
  float* t1 = (float*)alloc(NA * 4);
  u16* t1h = (u16*)alloc(NA * 2);
  u16* t1l = (u16*)alloc(NA * 2);
  float* ao2 = (float*)alloc(NA * 4);
  float* partials = (float*)alloc((size_t)kM * kNB * 4);
  float* rowinv = (float*)alloc(kM * 4);
  u16* wqkvh = (u16*)alloc((size_t)8 * 1536 * kD * 2);
  u16* wqkvl = (u16*)alloc((size_t)8 * 1536 * kD * 2);
  u16* woh = (u16*)alloc((size_t)8 * kD * kD * 2);
  u16* wol = (u16*)alloc((size_t)8 * kD * kD * 2);
  u16* w1h = (u16*)alloc((size_t)4 * kD * kD * 2);
  u16* w1l = (u16*)alloc((size_t)4 * kD * kD * 2);
  u16* w2h = (u16*)alloc((size_t)4 * kD * kD * 2);
  u16* w2l = (u16*)alloc((size_t)4 * kD * kD * 2);
  u16* embh = (u16*)alloc((size_t)kV * kD * 2);

  conv_qkv<<<dim3(8, 8, 24), 256, 0, stream>>>(Wq, Wk, Wv, wqkvh, wqkvl);
  conv_sq<<<dim3(8, 8, 16), 256, 0, stream>>>(Wo, w1, w2, woh, wol, w1h, w1l, w2h, w2l);
  conv_emb<<<kV * kD / 8 / 256, 256, 0, stream>>>(emb, embh);
  embed_kernel<<<kM, 256, 0, stream>>>(tokens, emb, x, xh, xl);

  for (int l = 0; l < kL; ++l) {
    for (int j = 0; j < 2; ++j) {
      const size_t lj = (size_t)(l * 2 + j);
      mgemm2<3, 64, 64, 2, 0, 0><<<dim3(kM / 64, 24), 256, 0, stream>>>(
          xh, xl, wqkvh + lj * 1536 * kD, wqkvl + lj * 1536 * kD,
          nullptr, qkvb, nullptr, nullptr, nullptr, kD, 1536);
      attn_kernel<<<dim3(kS / 64, kB * kH), 256, 0, stream>>>(
          qkvb, qkvb + NA, qkvb + 2 * NA, aoh, aol);
      mgemm2<3, 64, 64, 0, 0, 0><<<dim3(kM / 64, kD / 64), 256, 0, stream>>>(
          aoh, aol, woh + lj * kD * kD, wol + lj * kD * kD,
          t1, nullptr, nullptr, nullptr, nullptr, kD, kD);
      ln_kernel<<<kM, 256, 0, stream>>>(x, t1, lng + (size_t)(l * 3 + j) * kS * kD,
                                        lnb + (size_t)(l * 3 + j) * kS * kD, xh, xl);
    }
    mgemm2<3, 64, 64, 1, 1, 1><<<dim3(kM / 64, kD / 64), 256, 0, stream>>>(
        xh, xl, w1h + (size_t)l * kD * kD, w1l + (size_t)l * kD * kD,
        nullptr, t1h, t1l, b1 + (size_t)l * kD, nullptr, kD, kD);
    mgemm2<3, 64, 64, 0, 1, 0><<<dim3(kM / 64, kD / 64), 256, 0, stream>>>(
        t1h, t1l, w2h + (size_t)l * kD * kD, w2l + (size_t)l * kD * kD,
        ao2, nullptr, nullptr, b2 + (size_t)l * kD, nullptr, kD, kD);
    ln_kernel<<<kM, 256, 0, stream>>>(x, ao2, lng + (size_t)(l * 3 + 2) * kS * kD,
                                      lnb + (size_t)(l * 3 + 2) * kS * kD, xh, xl);
  }
  float* logits = (float*)d_out;
  mgemm2<1, 128, 128, 3, 0, 0><<<dim3(kM / 128, kNB), 256, 0, stream>>>(
      xh, nullptr, embh, nullptr, logits, nullptr, nullptr, nullptr, partials,
      kD, kV);
  rowsum_kernel<<<kM, 256, 0, stream>>>(partials, rowinv);
  scale_kernel<<<kM, 256, 0, stream>>>(logits, rowinv);
}

// Round 7
// 823.008 us; speedup vs baseline: 3.6966x; 1.0518x over previous
//
#include <hip/hip_runtime.h>
#include <hip/hip_bf16.h>

typedef unsigned short u16;
typedef short bf16x8 __attribute__((ext_vector_type(8)));
typedef float f32x4 __attribute__((ext_vector_type(4)));
typedef unsigned short u16x8 __attribute__((ext_vector_type(8)));

constexpr int kB = 2;
constexpr int kS = 1024;
constexpr int kD = 512;
constexpr int kH = 8;
constexpr int kDK = 64;
constexpr int kL = 4;
constexpr int kV = 32000;
constexpr int kM = kB * kS;   // 2048
constexpr int kNB = kV / 128; // 250

__device__ __forceinline__ u16 f2bh(float x) {
  unsigned u = __builtin_bit_cast(unsigned, x);
  unsigned r = u + 0x7fffu + ((u >> 16) & 1u);
  return (u16)(r >> 16);
}
__device__ __forceinline__ float bh2f(u16 h) {
  return __builtin_bit_cast(float, (unsigned)h << 16);
}
// async global->LDS, 16 bytes per lane (LDS dest must be wave-uniform+lane*16)
__device__ __forceinline__ void gload16(const u16* g, u16* l) {
  __builtin_amdgcn_global_load_lds(
      (const __attribute__((address_space(1))) unsigned int*)g,
      (__attribute__((address_space(3))) unsigned int*)l, 16, 0, 0);
}
// swizzled u16 index for element (row, k) in a [*][512] bf16 array
__device__ __forceinline__ size_t swz_idx(int row, int k) {
  return (size_t)row * kD + (k & ~63) + ((((k >> 3) & 7) ^ (row & 7)) << 3) + (k & 7);
}

// ------------------------------------------- weight conversion (transpose)
__global__ __launch_bounds__(256)
void conv_qkv(const float* __restrict__ Wq, const float* __restrict__ Wk,
              const float* __restrict__ Wv, u16* __restrict__ oh, u16* __restrict__ ol) {
  __shared__ float ld[64][65];
  const int kc = blockIdx.x, h = blockIdx.y, z = blockIdx.z;
  const int mat = z >> 3, lj = z & 7;
  const float* src = (mat == 0 ? Wq : mat == 1 ? Wk : Wv) +
                     ((size_t)(lj * kH + h)) * kD * kDK + (size_t)kc * 64 * kDK;
  const int t = threadIdx.x;
#pragma unroll
  for (int i = 0; i < 16; ++i) {
    const int idx = i * 256 + t;
    ld[idx >> 6][idx & 63] = src[idx];
  }
  __syncthreads();
  const int dkr = t >> 2, jb = t & 3;
  const size_t rowbase = ((size_t)lj * 1536 + mat * kD + h * kDK + dkr) * kD + kc * 64;
#pragma unroll
  for (int q = 0; q < 2; ++q) {
    const int jj = jb + q * 4;
    const int jsw = jj ^ (dkr & 7);
    u16x8 hi, lo;
#pragma unroll
    for (int e = 0; e < 8; ++e) {
      float v = ld[jj * 8 + e][dkr];
      hi[e] = f2bh(v);
      lo[e] = f2bh(v - bh2f(hi[e]));
    }
    *(u16x8*)&oh[rowbase + jsw * 8] = hi;
    *(u16x8*)&ol[rowbase + jsw * 8] = lo;
  }
}

__global__ __launch_bounds__(256)
void conv_sq(const float* __restrict__ Wo, const float* __restrict__ w1,
             const float* __restrict__ w2, u16* __restrict__ woh, u16* __restrict__ wol,
             u16* __restrict__ w1h, u16* __restrict__ w1l,
             u16* __restrict__ w2h, u16* __restrict__ w2l) {
  __shared__ float ld[64][65];
  const int kc = blockIdx.x, nc = blockIdx.y, mid = blockIdx.z;
  const float* src;
  u16 *dh, *dl;
  if (mid < 8) { src = Wo + (size_t)mid * kD * kD; dh = woh + (size_t)mid * kD * kD; dl = wol + (size_t)mid * kD * kD; }
  else if (mid < 12) { int l = mid - 8; src = w1 + (size_t)l * kD * kD; dh = w1h + (size_t)l * kD * kD; dl = w1l + (size_t)l * kD * kD; }
  else { int l = mid - 12; src = w2 + (size_t)l * kD * kD; dh = w2h + (size_t)l * kD * kD; dl = w2l + (size_t)l * kD * kD; }
  const int t = threadIdx.x;
#pragma unroll
  for (int i = 0; i < 16; ++i) {
    const int idx = i * 256 + t;
    const int kl = idx >> 6, nl = idx & 63;
    ld[kl][nl] = src[(size_t)(kc * 64 + kl) * kD + nc * 64 + nl];
  }
  __syncthreads();
  const int nr = t >> 2, jb = t & 3;
  const size_t rowbase = (size_t)(nc * 64 + nr) * kD + kc * 64;
#pragma unroll
  for (int q = 0; q < 2; ++q) {
    const int jj = jb + q * 4;
    const int jsw = jj ^ (nr & 7);
    u16x8 hi, lo;
#pragma unroll
    for (int e = 0; e < 8; ++e) {
      float v = ld[jj * 8 + e][nr];
      hi[e] = f2bh(v);
      lo[e] = f2bh(v - bh2f(hi[e]));
    }
    *(u16x8*)&dh[rowbase + jsw * 8] = hi;
    *(u16x8*)&dl[rowbase + jsw * 8] = lo;
  }
}

__global__ __launch_bounds__(256)
void conv_emb(const float* __restrict__ emb, u16* __restrict__ oh) {
  const int chunk = blockIdx.x * 256 + threadIdx.x;
  const int n = chunk >> 6, j = chunk & 63;
  const float* s = &emb[(size_t)n * kD + j * 8];
  float4 a = *(const float4*)s, b = *(const float4*)(s + 4);
  u16x8 hi;
  hi[0] = f2bh(a.x); hi[1] = f2bh(a.y); hi[2] = f2bh(a.z); hi[3] = f2bh(a.w);
  hi[4] = f2bh(b.x); hi[5] = f2bh(b.y); hi[6] = f2bh(b.z); hi[7] = f2bh(b.w);
  *(u16x8*)&oh[(size_t)n * kD + (j & ~7) * 8 + (((j & 7) ^ (n & 7)) << 3)] = hi;
}

// ---------------------------------------------------------------- embed + PE
__global__ __launch_bounds__(256)
void embed_kernel(const int* __restrict__ tokens, const float* __restrict__ emb,
                  float* __restrict__ x, u16* __restrict__ xh, u16* __restrict__ xl) {
  const int row = blockIdx.x;
  const int s = row & (kS - 1);
  const int tok = tokens[row];
  const float scl = sqrtf((float)kD);
  for (int d = threadIdx.x; d < kD; d += 256) {
    float e = emb[(size_t)tok * kD + d];
    float den = powf(10000.0f, 2.0f * (float)d / (float)kD);
    float ang = (float)s / den;
    float pe = ((d & 1) == 0) ? sinf(ang) : cosf(ang);
    float o = (e + pe) * scl;
    x[(size_t)row * kD + d] = o;
    u16 hi = f2bh(o);
    size_t p = swz_idx(row, d);
    xh[p] = hi;
    xl[p] = f2bh(o - bh2f(hi));
  }
}

// --------------------------------------------------- MFMA GEMM, bf16 inputs
// C = A @ B^T. A: [M][K] bf16 (hi[,lo]) pre-swizzled. B: [N][K] pre-swizzled.
// 2-phase double-buffered K-loop with global_load_lds(16B) staging.
// OUT: 0 fp32 [M][Nd]; 1 bf16 hi/lo swizzled [M][512]; 2 qkv bf16 scatter;
//      3 bf16 exp(c) [M][Nd] + deterministic per-row partial sums.
template <int SPLIT, int BM, int BN, int OUT, int BIAS, int RELU>
__global__ __launch_bounds__(256)
void mgemm2(const u16* __restrict__ Ah, const u16* __restrict__ Al,
            const u16* __restrict__ Bh, const u16* __restrict__ Bl,
            float* __restrict__ Cf, u16* __restrict__ Ch, u16* __restrict__ Cl,
            const float* __restrict__ bias, float* __restrict__ partials,
            int Kd, int Nd) {
  static_assert(BM == BN, "");
  constexpr int MF = BM / 32, NF = BN / 32;
  constexpr int TA = BM * 64;                       // u16 per tile
  constexpr int NT = (SPLIT == 3 ? 4 : 2);          // tiles per buffer
  constexpr int BUF = NT * TA;
  __shared__ __align__(16) u16 lds[2 * BUF];
  __shared__ float plds[OUT == 3 ? 2 * BM : 1];
  const int t = threadIdx.x;
  const int lane = t & 63, g = lane >> 4, li = lane & 15;
  const int w = t >> 6, wr = w >> 1, wc = w & 1;
  const int m0 = blockIdx.x * BM, n0 = blockIdx.y * BN;

  f32x4 acc[MF][NF];
#pragma unroll
  for (int i = 0; i < MF; ++i)
#pragma unroll
    for (int j = 0; j < NF; ++j) acc[i][j] = (f32x4){0.f, 0.f, 0.f, 0.f};

  auto stage = [&](int c, int k0) {
    u16* base = &lds[c * BUF];
#pragma unroll
    for (int it = 0; it < BM / 32; ++it) {
      const int idx = it * 256 + t;
      const int r = idx >> 3, j = (idx & 7) * 8;
      gload16(&Ah[(size_t)(m0 + r) * Kd + k0 + j], &base[idx * 8]);
      if (SPLIT == 3)
        gload16(&Al[(size_t)(m0 + r) * Kd + k0 + j], &base[TA + idx * 8]);
      gload16(&Bh[(size_t)(n0 + r) * Kd + k0 + j],
              &base[(SPLIT == 3 ? 2 : 1) * TA + idx * 8]);
      if (SPLIT == 3)
        gload16(&Bl[(size_t)(n0 + r) * Kd + k0 + j], &base[3 * TA + idx * 8]);
    }
  };
  auto compute = [&](int c) {
    const u16* base = &lds[c * BUF];
#pragma unroll
    for (int s = 0; s < 2; ++s) {
      const int s4g = s * 4 + g;
      bf16x8 fah[MF], fbh[NF], fal[SPLIT == 3 ? MF : 1], fbl[SPLIT == 3 ? NF : 1];
#pragma unroll
      for (int fm = 0; fm < MF; ++fm) {
        const int row = wr * (BM / 2) + fm * 16 + li;
        const int off = row * 64 + ((s4g ^ (row & 7)) << 3);
        fah[fm] = *(const bf16x8*)&base[off];
        if (SPLIT == 3) fal[fm] = *(const bf16x8*)&base[TA + off];
      }
#pragma unroll
      for (int fn = 0; fn < NF; ++fn) {
        const int row = wc * (BN / 2) + fn * 16 + li;
        const int off = row * 64 + ((s4g ^ (row & 7)) << 3);
        fbh[fn] = *(const bf16x8*)&base[(SPLIT == 3 ? 2 : 1) * TA + off];
        if (SPLIT == 3) fbl[fn] = *(const bf16x8*)&base[3 * TA + off];
      }
#pragma unroll
      for (int fm = 0; fm < MF; ++fm)
#pragma unroll
        for (int fn = 0; fn < NF; ++fn) {
          acc[fm][fn] = __builtin_amdgcn_mfma_f32_16x16x32_bf16(
              fah[fm], fbh[fn], acc[fm][fn], 0, 0, 0);
          if (SPLIT == 3) {
            acc[fm][fn] = __builtin_amdgcn_mfma_f32_16x16x32_bf16(
                fal[fm], fbh[fn], acc[fm][fn], 0, 0, 0);
            acc[fm][fn] = __builtin_amdgcn_mfma_f32_16x16x32_bf16(
                fah[fm], fbl[fn], acc[fm][fn], 0, 0, 0);
          }
        }
    }
  };

  stage(0, 0);
  __syncthreads();                 // drains vmcnt(0): tile 0 resident
  int cur = 0;
  for (int k0 = 64; k0 < Kd; k0 += 64) {
    stage(cur ^ 1, k0);            // issue next-tile DMA (no wait)
    compute(cur);                  // hide DMA latency under ds_read+MFMA
    __syncthreads();               // one drain+barrier per K-step
    cur ^= 1;
  }
  compute(cur);

  // epilogue: D col = lane&15, row = (lane>>4)*4 + reg
#pragma unroll
  for (int fm = 0; fm < MF; ++fm)
#pragma unroll
    for (int fn = 0; fn < NF; ++fn)
#pragma unroll
      for (int r = 0; r < 4; ++r) {
        const int m = m0 + wr * (BM / 2) + fm * 16 + g * 4 + r;
        const int n = n0 + wc * (BN / 2) + fn * 16 + li;
        float c = acc[fm][fn][r];
        if (BIAS) c += bias[n];
        if (RELU) c = fmaxf(c, 0.0f);
        if (OUT == 0) {
          Cf[(size_t)m * Nd + n] = c;
        } else if (OUT == 1) {
          u16 hi = f2bh(c);
          size_t p = swz_idx(m, n);
          Ch[p] = hi;
          Cl[p] = f2bh(c - bh2f(hi));
        } else if (OUT == 2) {
          const int mat = n >> 9, h = (n >> 6) & 7, dk = n & 63;
          const int b_ = m >> 10, s_ = m & (kS - 1);
          Ch[(size_t)mat * ((size_t)kM * kDK * kH / 8) * 8 +
             (((size_t)(b_ * kH + h) * kS + s_) * kDK + dk)] = f2bh(c);
        } else {
          u16 q = f2bh(__expf(c));
          Ch[(size_t)m * Nd + n] = q;
          acc[fm][fn][r] = bh2f(q);   // numerator/denominator consistent
        }
      }
  if (OUT == 3) {
#pragma unroll
    for (int fm = 0; fm < MF; ++fm)
#pragma unroll
      for (int r = 0; r < 4; ++r) {
        float sv = 0.f;
#pragma unroll
        for (int fn = 0; fn < NF; ++fn) sv += acc[fm][fn][r];
        sv += __shfl_xor(sv, 1); sv += __shfl_xor(sv, 2);
        sv += __shfl_xor(sv, 4); sv += __shfl_xor(sv, 8);
        if (li == 0) plds[wc * BM + wr * (BM / 2) + fm * 16 + g * 4 + r] = sv;
      }
    __syncthreads();
    if (t < BM)
      partials[(size_t)(m0 + t) * gridDim.y + blockIdx.y] = plds[t] + plds[BM + t];
  }
}

// --------------------------------------------- MFMA flash attention (bf16)
__global__ __launch_bounds__(256)
void attn_kernel(const u16* __restrict__ qg, const u16* __restrict__ kg,
                 const u16* __restrict__ vg, u16* __restrict__ aoh,
                 u16* __restrict__ aol) {
  __shared__ __align__(16) u16 Kt[2][64][40];
  __shared__ __align__(16) u16 Vt[2][64][40];
  __shared__ __align__(16) u16 Pt[2][64][40];
  const int t = threadIdx.x;
  const int lane = t & 63;
  const int g = lane >> 4, li = lane & 15;
  const int w = t >> 6;
  const int bh = blockIdx.y;
  const int q0 = blockIdx.x * 64;
  const size_t base = (size_t)bh * kS * kDK;
  {
    const int r = t >> 2, dq = (t & 3) * 16;
    const u16* src = &qg[base + (size_t)(q0 + r) * kDK + dq];
    u16x8 a = *(const u16x8*)src;
    u16x8 b = *(const u16x8*)(src + 8);
    *(u16x8*)&Kt[dq >> 5][r][dq & 31] = a;
    *(u16x8*)&Kt[dq >> 5][r][(dq & 31) + 8] = b;
  }
  __syncthreads();
  bf16x8 qf0 = *(const bf16x8*)&Kt[0][w * 16 + li][g * 8];
  bf16x8 qf1 = *(const bf16x8*)&Kt[1][w * 16 + li][g * 8];

  float m_[4] = {-1e30f, -1e30f, -1e30f, -1e30f};
  float l_[4] = {0.f, 0.f, 0.f, 0.f};
  f32x4 apv[4];
#pragma unroll
  for (int i = 0; i < 4; ++i) apv[i] = (f32x4){0.f, 0.f, 0.f, 0.f};

  for (int kt = 0; kt < kS / 64; ++kt) {
    __syncthreads();
    {
      const int r = t >> 2, dq = (t & 3) * 16;
      const u16* ks = &kg[base + (size_t)(kt * 64 + r) * kDK + dq];
      u16x8 a = *(const u16x8*)ks;
      u16x8 b = *(const u16x8*)(ks + 8);
      *(u16x8*)&Kt[dq >> 5][r][dq & 31] = a;
      *(u16x8*)&Kt[dq >> 5][r][(dq & 31) + 8] = b;
      const u16* vs = &vg[base + (size_t)(kt * 64 + r) * kDK + dq];
      u16x8 va = *(const u16x8*)vs;
      u16x8 vb = *(const u16x8*)(vs + 8);
      const int vc = r >> 5, ko = (r & 31) >> 3, kp = r & 7;
#pragma unroll
      for (int i = 0; i < 8; ++i) {
        const int d = dq + i;
        Vt[vc][d][((ko ^ (d >> 4)) << 3) | kp] = va[i];
      }
#pragma unroll
      for (int i = 0; i < 8; ++i) {
        const int d = dq + 8 + i;
        Vt[vc][d][((ko ^ (d >> 4)) << 3) | kp] = vb[i];
      }
    }
    __syncthreads();
    f32x4 s[4];
#pragma unroll
    for (int nf = 0; nf < 4; ++nf) {
      bf16x8 k0 = *(const bf16x8*)&Kt[0][nf * 16 + li][g * 8];
      bf16x8 k1 = *(const bf16x8*)&Kt[1][nf * 16 + li][g * 8];
      f32x4 sa = (f32x4){0.f, 0.f, 0.f, 0.f};
      sa = __builtin_amdgcn_mfma_f32_16x16x32_bf16(qf0, k0, sa, 0, 0, 0);
      sa = __builtin_amdgcn_mfma_f32_16x16x32_bf16(qf1, k1, sa, 0, 0, 0);
      s[nf] = sa;
    }
    float corr[4];
#pragma unroll
    for (int r = 0; r < 4; ++r) {
      float tm = fmaxf(fmaxf(s[0][r], s[1][r]), fmaxf(s[2][r], s[3][r])) * 0.125f;
      tm = fmaxf(tm, __shfl_xor(tm, 1));
      tm = fmaxf(tm, __shfl_xor(tm, 2));
      tm = fmaxf(tm, __shfl_xor(tm, 4));
      tm = fmaxf(tm, __shfl_xor(tm, 8));
      const float nm = fmaxf(m_[r], tm);
      corr[r] = __expf(m_[r] - nm);
      m_[r] = nm;
    }
    float tsum[4] = {0.f, 0.f, 0.f, 0.f};
    u16 pb[4][4];
#pragma unroll
    for (int nf = 0; nf < 4; ++nf)
#pragma unroll
      for (int r = 0; r < 4; ++r) {
        float p = __expf(s[nf][r] * 0.125f - m_[r]);
        tsum[r] += p;
        pb[nf][r] = f2bh(p);
      }
#pragma unroll
    for (int r = 0; r < 4; ++r) {
      float ts = tsum[r];
      ts += __shfl_xor(ts, 1); ts += __shfl_xor(ts, 2);
      ts += __shfl_xor(ts, 4); ts += __shfl_xor(ts, 8);
      l_[r] = l_[r] * corr[r] + ts;
#pragma unroll
      for (int nf = 0; nf < 4; ++nf) apv[nf][r] *= corr[r];
    }
#pragma unroll
    for (int nf = 0; nf < 4; ++nf)
#pragma unroll
      for (int r = 0; r < 4; ++r)
        Pt[nf >> 1][w * 16 + g * 4 + r][(nf & 1) * 16 + li] = pb[nf][r];
    bf16x8 p0 = *(const bf16x8*)&Pt[0][w * 16 + li][g * 8];
    bf16x8 p1 = *(const bf16x8*)&Pt[1][w * 16 + li][g * 8];
#pragma unroll
    for (int nf = 0; nf < 4; ++nf) {
      bf16x8 v0 = *(const bf16x8*)&Vt[0][nf * 16 + li][((g ^ nf) & 3) * 8];
      bf16x8 v1 = *(const bf16x8*)&Vt[1][nf * 16 + li][((g ^ nf) & 3) * 8];
      apv[nf] = __builtin_amdgcn_mfma_f32_16x16x32_bf16(p0, v0, apv[nf], 0, 0, 0);
      apv[nf] = __builtin_amdgcn_mfma_f32_16x16x32_bf16(p1, v1, apv[nf], 0, 0, 0);
    }
  }
  const int b_ = bh >> 3, h_ = bh & 7;
#pragma unroll
  for (int r = 0; r < 4; ++r) {
    const float inv = 1.0f / l_[r];
    const int row = q0 + w * 16 + g * 4 + r;
    const int m = b_ * kS + row;
#pragma unroll
    for (int nf = 0; nf < 4; ++nf) {
      const int d = h_ * kDK + nf * 16 + li;
      float o = apv[nf][r] * inv;
      u16 hi = f2bh(o);
      size_t p = swz_idx(m, d);
      aoh[p] = hi;
      aol[p] = f2bh(o - bh2f(hi));
    }
  }
}

// --------------------------------------------- residual + LayerNorm in place
__global__ __launch_bounds__(256)
void ln_kernel(float* __restrict__ x, const float* __restrict__ h,
               const float* __restrict__ gain, const float* __restrict__ bias,
               u16* __restrict__ xh, u16* __restrict__ xl) {
  const int row = blockIdx.x;
  const int s = row & (kS - 1);
  const int t = threadIdx.x;
  float* xr = x + (size_t)row * kD;
  const float* hr = h + (size_t)row * kD;
  const float v0 = xr[t] + hr[t];
  const float v1 = xr[t + 256] + hr[t + 256];
  float sum = v0 + v1;
  float sq = v0 * v0 + v1 * v1;
#pragma unroll
  for (int off = 1; off < 64; off <<= 1) {
    sum += __shfl_xor(sum, off);
    sq += __shfl_xor(sq, off);
  }
  __shared__ float rs[4], rq[4];
  if ((t & 63) == 0) { rs[t >> 6] = sum; rq[t >> 6] = sq; }
  __syncthreads();
  sum = rs[0] + rs[1] + rs[2] + rs[3];
  sq = rq[0] + rq[1] + rq[2] + rq[3];
  const float mean = sum * (1.0f / kD);
  const float var = fmaxf(sq * (1.0f / kD) - mean * mean, 0.0f);
  const float inv = 1.0f / (sqrtf(var) + 1e-6f);
  const float* gr = gain + (size_t)s * kD;
  const float* br = bias + (size_t)s * kD;
  const float o0 = gr[t] * inv * (v0 - mean) + br[t];
  const float o1 = gr[t + 256] * inv * (v1 - mean) + br[t + 256];
  xr[t] = o0;
  xr[t + 256] = o1;
  {
    u16 hi = f2bh(o0);
    size_t p = swz_idx(row, t);
    xh[p] = hi; xl[p] = f2bh(o0 - bh2f(hi));
  }
  {
    u16 hi = f2bh(o1);
    size_t p = swz_idx(row, t + 256);
    xh[p] = hi; xl[p] = f2bh(o1 - bh2f(hi));
  }
}

// ---------------- fused rowsum + scale: p = bf16exp / sum, write fp32 d_out
__global__ __launch_bounds__(256)
void scale_kernel(const u16* __restrict__ expb, const float* __restrict__ partials,
                  float* __restrict__ out) {
  const int row = blockIdx.x;
  const int t = threadIdx.x;
  float s = (t < kNB) ? partials[(size_t)row * kNB + t] : 0.f;
#pragma unroll
  for (int off = 1; off < 64; off <<= 1) s += __shfl_xor(s, off);
  __shared__ float red[4];
  if ((t & 63) == 0) red[t >> 6] = s;
  __syncthreads();
  const float inv = 1.0f / (red[0] + red[1] + red[2] + red[3]);
  const u16x8* src = (const u16x8*)(expb + (size_t)row * kV);
  float4* dst = (float4*)(out + (size_t)row * kV);
  for (int i = t; i < kV / 8; i += 256) {
    u16x8 v = src[i];
    float4 a = make_float4(bh2f(v[0]) * inv, bh2f(v[1]) * inv,
                           bh2f(v[2]) * inv, bh2f(v[3]) * inv);
    float4 b = make_float4(bh2f(v[4]) * inv, bh2f(v[5]) * inv,
                           bh2f(v[6]) * inv, bh2f(v[7]) * inv);
    dst[i * 2] = a;
    dst[i * 2 + 1] = b;
  }
}

// ---------------------------------------------------------------------------
extern "C" void kernel_launch(void* const* d_in, const int* in_sizes, int n_in,
                              void* d_out, int out_size, void* d_ws, size_t ws_size,
                              hipStream_t stream) {
  (void)in_sizes; (void)n_in; (void)out_size; (void)ws_size;
  const int* tokens = (const int*)d_in[0];
  const float* emb = (const float*)d_in[1];
  const float* Wq = (const float*)d_in[2];
  const float* Wk = (const float*)d_in[3];
  const float* Wv = (const float*)d_in[4];
  const float* Wo = (const float*)d_in[5];
  const float* lng = (const float*)d_in[6];
  const float* lnb = (const float*)d_in[7];
  const float* w1 = (const float*)d_in[8];
  const float* b1 = (const float*)d_in[9];
  const float* w2 = (const float*)d_in[10];
  const float* b2 = (const float*)d_in[11];

  size_t off = 0;
  auto alloc = [&](size_t bytes) {
    void* p = (char*)d_ws + off;
    off += (bytes + 255) & ~(size_t)255;
    return p;
  };
  const size_t NA = (size_t)kM * kD;
  float* x = (float*)alloc(NA * 4);
  u16* xh = (u16*)alloc(NA * 2);
  u16* xl = (u16*)alloc(NA * 2);
  u16* qkvb = (u16*)alloc(3 * NA * 2);
  u16* aoh = (u16*)alloc(NA * 2);
  u16* aol = (u16*)alloc(NA * 2);
  float* t1 = (float*)alloc(NA * 4);
  u16* t1h = (u16*)alloc(NA * 2);
  u16* t1l = (u16*)alloc(NA * 2);
  float* ao2 = (float*)alloc(NA * 4);
  float* partials = (float*)alloc((size_t)kM * kNB * 4);
  u16* expb = (u16*)alloc((size_t)kM * kV * 2);     // 131 MB bf16 exp-logits
  u16* wqkvh = (u16*)alloc((size_t)8 * 1536 * kD * 2);
  u16* wqkvl = (u16*)alloc((size_t)8 * 1536 * kD * 2);
  u16* woh = (u16*)alloc((size_t)8 * kD * kD * 2);
  u16* wol = (u16*)alloc((size_t)8 * kD * kD * 2);
  u16* w1h = (u16*)alloc((size_t)4 * kD * kD * 2);
  u16* w1l = (u16*)alloc((size_t)4 * kD * kD * 2);
  u16* w2h = (u16*)alloc((size_t)4 * kD * kD * 2);
  u16* w2l = (u16*)alloc((size_t)4 * kD * kD * 2);
  u16* embh = (u16*)alloc((size_t)kV * kD * 2);

  conv_qkv<<<dim3(8, 8, 24), 256, 0, stream>>>(Wq, Wk, Wv, wqkvh, wqkvl);
  conv_sq<<<dim3(8, 8, 16), 256, 0, stream>>>(Wo, w1, w2, woh, wol, w1h, w1l, w2h, w2l);
  conv_emb<<<kV * kD / 8 / 256, 256, 0, stream>>>(emb, embh);
  embed_kernel<<<kM, 256, 0, stream>>>(tokens, emb, x, xh, xl);

  for (int l = 0; l < kL; ++l) {
    for (int j = 0; j < 2; ++j) {
      const size_t lj = (size_t)(l * 2 + j);
      mgemm2<3, 128, 128, 2, 0, 0><<<dim3(kM / 128, 12), 256, 0, stream>>>(
          xh, xl, wqkvh + lj * 1536 * kD, wqkvl + lj * 1536 * kD,
          nullptr, qkvb, nullptr, nullptr, nullptr, kD, 1536);
      attn_kernel<<<dim3(kS / 64, kB * kH), 256, 0, stream>>>(
          qkvb, qkvb + NA, qkvb + 2 * NA, aoh, aol);
      mgemm2<3, 64, 64, 0, 0, 0><<<dim3(kM / 64, kD / 64), 256, 0, stream>>>(
          aoh, aol, woh + lj * kD * kD, wol + lj * kD * kD,
          t1, nullptr, nullptr, nullptr, nullptr, kD, kD);
      ln_kernel<<<kM, 256, 0, stream>>>(x, t1, lng + (size_t)(l * 3 + j) * kS * kD,
                                        lnb + (size_t)(l * 3 + j) * kS * kD, xh, xl);
    }
    mgemm2<3, 64, 64, 1, 1, 1><<<dim3(kM / 64, kD / 64), 256, 0, stream>>>(
        xh, xl, w1h + (size_t)l * kD * kD, w1l + (size_t)l * kD * kD,
        nullptr, t1h, t1l, b1 + (size_t)l * kD, nullptr, kD, kD);
    mgemm2<3, 64, 64, 0, 1, 0><<<dim3(kM / 64, kD / 64), 256, 0, stream>>>(
        t1h, t1l, w2h + (size_t)l * kD * kD, w2l + (size_t)l * kD * kD,
        ao2, nullptr, nullptr, b2 + (size_t)l * kD, nullptr, kD, kD);
    ln_kernel<<<kM, 256, 0, stream>>>(x, ao2, lng + (size_t)(l * 3 + 2) * kS * kD,
                                      lnb + (size_t)(l * 3 + 2) * kS * kD, xh, xl);
  }
  // vocab: bf16 exp(x @ emb^T) -> expb + partials; then fused rowsum+scale
  mgemm2<1, 128, 128, 3, 0, 0><<<dim3(kM / 128, kNB), 256, 0, stream>>>(
      xh, nullptr, embh, nullptr, nullptr, expb, nullptr, nullptr, partials,
      kD, kV);
  scale_kernel<<<kM, 256, 0, stream>>>(expb, partials, (float*)d_out);
}

// Round 8
// 669.391 us; speedup vs baseline: 4.5449x; 1.2295x over previous
//
#include <hip/hip_runtime.h>
#include <hip/hip_bf16.h>

typedef unsigned short u16;
typedef _Float16 f16x8 __attribute__((ext_vector_type(8)));
typedef float f32x4 __attribute__((ext_vector_type(4)));
typedef unsigned short u16x8 __attribute__((ext_vector_type(8)));

constexpr int kB = 2;
constexpr int kS = 1024;
constexpr int kD = 512;
constexpr int kH = 8;
constexpr int kDK = 64;
constexpr int kL = 4;
constexpr int kV = 32000;
constexpr int kM = kB * kS;   // 2048
constexpr int kNB = kV / 128; // 250

__device__ __forceinline__ u16 f2fh(float x) {           // fp16 RTN
  _Float16 h = (_Float16)x;
  return __builtin_bit_cast(u16, h);
}
__device__ __forceinline__ float fh2f(u16 h) {
  return (float)__builtin_bit_cast(_Float16, h);
}
__device__ __forceinline__ u16 f2bh(float x) {           // bf16 RTN (exp store)
  unsigned u = __builtin_bit_cast(unsigned, x);
  unsigned r = u + 0x7fffu + ((u >> 16) & 1u);
  return (u16)(r >> 16);
}
__device__ __forceinline__ float bh2f(u16 h) {
  return __builtin_bit_cast(float, (unsigned)h << 16);
}
__device__ __forceinline__ void gload16(const u16* g, u16* l) {
  __builtin_amdgcn_global_load_lds(
      (const __attribute__((address_space(1))) unsigned int*)g,
      (__attribute__((address_space(3))) unsigned int*)l, 16, 0, 0);
}
// swizzled u16 index for element (row, k) in a [*][512] fp16 array
__device__ __forceinline__ size_t swz_idx(int row, int k) {
  return (size_t)row * kD + (k & ~63) + ((((k >> 3) & 7) ^ (row & 7)) << 3) + (k & 7);
}

// ------------------------------------------- weight conversion (transpose)
__global__ __launch_bounds__(256)
void conv_qkv(const float* __restrict__ Wq, const float* __restrict__ Wk,
              const float* __restrict__ Wv, u16* __restrict__ oh) {
  __shared__ float ld[64][65];
  const int kc = blockIdx.x, h = blockIdx.y, z = blockIdx.z;
  const int mat = z >> 3, lj = z & 7;
  const float* src = (mat == 0 ? Wq : mat == 1 ? Wk : Wv) +
                     ((size_t)(lj * kH + h)) * kD * kDK + (size_t)kc * 64 * kDK;
  const int t = threadIdx.x;
#pragma unroll
  for (int i = 0; i < 16; ++i) {
    const int idx = i * 256 + t;
    ld[idx >> 6][idx & 63] = src[idx];
  }
  __syncthreads();
  const int dkr = t >> 2, jb = t & 3;
  const size_t rowbase = ((size_t)lj * 1536 + mat * kD + h * kDK + dkr) * kD + kc * 64;
#pragma unroll
  for (int q = 0; q < 2; ++q) {
    const int jj = jb + q * 4;
    const int jsw = jj ^ (dkr & 7);
    u16x8 hi;
#pragma unroll
    for (int e = 0; e < 8; ++e) hi[e] = f2fh(ld[jj * 8 + e][dkr]);
    *(u16x8*)&oh[rowbase + jsw * 8] = hi;
  }
}

__global__ __launch_bounds__(256)
void conv_sq(const float* __restrict__ Wo, const float* __restrict__ w1,
             const float* __restrict__ w2, u16* __restrict__ woh,
             u16* __restrict__ w1h, u16* __restrict__ w2h) {
  __shared__ float ld[64][65];
  const int kc = blockIdx.x, nc = blockIdx.y, mid = blockIdx.z;
  const float* src;
  u16* dh;
  if (mid < 8) { src = Wo + (size_t)mid * kD * kD; dh = woh + (size_t)mid * kD * kD; }
  else if (mid < 12) { int l = mid - 8; src = w1 + (size_t)l * kD * kD; dh = w1h + (size_t)l * kD * kD; }
  else { int l = mid - 12; src = w2 + (size_t)l * kD * kD; dh = w2h + (size_t)l * kD * kD; }
  const int t = threadIdx.x;
#pragma unroll
  for (int i = 0; i < 16; ++i) {
    const int idx = i * 256 + t;
    const int kl = idx >> 6, nl = idx & 63;
    ld[kl][nl] = src[(size_t)(kc * 64 + kl) * kD + nc * 64 + nl];
  }
  __syncthreads();
  const int nr = t >> 2, jb = t & 3;
  const size_t rowbase = (size_t)(nc * 64 + nr) * kD + kc * 64;
#pragma unroll
  for (int q = 0; q < 2; ++q) {
    const int jj = jb + q * 4;
    const int jsw = jj ^ (nr & 7);
    u16x8 hi;
#pragma unroll
    for (int e = 0; e < 8; ++e) hi[e] = f2fh(ld[jj * 8 + e][nr]);
    *(u16x8*)&dh[rowbase + jsw * 8] = hi;
  }
}

__global__ __launch_bounds__(256)
void conv_emb(const float* __restrict__ emb, u16* __restrict__ oh) {
  const int chunk = blockIdx.x * 256 + threadIdx.x;
  const int n = chunk >> 6, j = chunk & 63;
  const float* s = &emb[(size_t)n * kD + j * 8];
  float4 a = *(const float4*)s, b = *(const float4*)(s + 4);
  u16x8 hi;
  hi[0] = f2fh(a.x); hi[1] = f2fh(a.y); hi[2] = f2fh(a.z); hi[3] = f2fh(a.w);
  hi[4] = f2fh(b.x); hi[5] = f2fh(b.y); hi[6] = f2fh(b.z); hi[7] = f2fh(b.w);
  *(u16x8*)&oh[(size_t)n * kD + (j & ~7) * 8 + (((j & 7) ^ (n & 7)) << 3)] = hi;
}

// ---------------------------------------------------------------- embed + PE
__global__ __launch_bounds__(256)
void embed_kernel(const int* __restrict__ tokens, const float* __restrict__ emb,
                  float* __restrict__ x, u16* __restrict__ xh) {
  const int row = blockIdx.x;
  const int s = row & (kS - 1);
  const int tok = tokens[row];
  const float scl = sqrtf((float)kD);
  for (int d = threadIdx.x; d < kD; d += 256) {
    float e = emb[(size_t)tok * kD + d];
    float den = powf(10000.0f, 2.0f * (float)d / (float)kD);
    float ang = (float)s / den;
    float pe = ((d & 1) == 0) ? sinf(ang) : cosf(ang);
    float o = (e + pe) * scl;
    x[(size_t)row * kD + d] = o;
    xh[swz_idx(row, d)] = f2fh(o);
  }
}

// --------------------------------------------------- MFMA GEMM, fp16 inputs
// C = A @ B^T. A: [M][K] fp16 pre-swizzled. B: [N][K] fp16 pre-swizzled.
// 2-phase double-buffered K-loop with global_load_lds(16B) staging.
// OUT: 0 fp32 [M][Nd]; 1 fp16 swizzled [M][512]; 2 qkv fp16 scatter;
//      3 bf16 exp(c) [M][Nd] + deterministic per-row partial sums.
template <int BM, int BN, int OUT, int BIAS, int RELU>
__global__ __launch_bounds__(256)
void mgemm2(const u16* __restrict__ Ah, const u16* __restrict__ Bh,
            float* __restrict__ Cf, u16* __restrict__ Ch,
            const float* __restrict__ bias, float* __restrict__ partials,
            int Kd, int Nd) {
  static_assert(BM == BN, "");
  constexpr int MF = BM / 32, NF = BN / 32;
  constexpr int TA = BM * 64;                       // u16 per tile
  constexpr int BUF = 2 * TA;                       // A + B
  __shared__ __align__(16) u16 lds[2 * BUF];
  __shared__ float plds[OUT == 3 ? 2 * BM : 1];
  const int t = threadIdx.x;
  const int lane = t & 63, g = lane >> 4, li = lane & 15;
  const int w = t >> 6, wr = w >> 1, wc = w & 1;
  const int m0 = blockIdx.x * BM, n0 = blockIdx.y * BN;

  f32x4 acc[MF][NF];
#pragma unroll
  for (int i = 0; i < MF; ++i)
#pragma unroll
    for (int j = 0; j < NF; ++j) acc[i][j] = (f32x4){0.f, 0.f, 0.f, 0.f};

  auto stage = [&](int c, int k0) {
    u16* base = &lds[c * BUF];
#pragma unroll
    for (int it = 0; it < BM / 32; ++it) {
      const int idx = it * 256 + t;
      const int r = idx >> 3, j = (idx & 7) * 8;
      gload16(&Ah[(size_t)(m0 + r) * Kd + k0 + j], &base[idx * 8]);
      gload16(&Bh[(size_t)(n0 + r) * Kd + k0 + j], &base[TA + idx * 8]);
    }
  };
  auto compute = [&](int c) {
    const u16* base = &lds[c * BUF];
#pragma unroll
    for (int s = 0; s < 2; ++s) {
      const int s4g = s * 4 + g;
      f16x8 fah[MF], fbh[NF];
#pragma unroll
      for (int fm = 0; fm < MF; ++fm) {
        const int row = wr * (BM / 2) + fm * 16 + li;
        fah[fm] = *(const f16x8*)&base[row * 64 + ((s4g ^ (row & 7)) << 3)];
      }
#pragma unroll
      for (int fn = 0; fn < NF; ++fn) {
        const int row = wc * (BN / 2) + fn * 16 + li;
        fbh[fn] = *(const f16x8*)&base[TA + row * 64 + ((s4g ^ (row & 7)) << 3)];
      }
#pragma unroll
      for (int fm = 0; fm < MF; ++fm)
#pragma unroll
        for (int fn = 0; fn < NF; ++fn)
          acc[fm][fn] = __builtin_amdgcn_mfma_f32_16x16x32_f16(
              fah[fm], fbh[fn], acc[fm][fn], 0, 0, 0);
    }
  };

  stage(0, 0);
  __syncthreads();
  int cur = 0;
  for (int k0 = 64; k0 < Kd; k0 += 64) {
    stage(cur ^ 1, k0);
    compute(cur);
    __syncthreads();
    cur ^= 1;
  }
  compute(cur);

  // epilogue: D col = lane&15, row = (lane>>4)*4 + reg
#pragma unroll
  for (int fm = 0; fm < MF; ++fm)
#pragma unroll
    for (int fn = 0; fn < NF; ++fn)
#pragma unroll
      for (int r = 0; r < 4; ++r) {
        const int m = m0 + wr * (BM / 2) + fm * 16 + g * 4 + r;
        const int n = n0 + wc * (BN / 2) + fn * 16 + li;
        float c = acc[fm][fn][r];
        if (BIAS) c += bias[n];
        if (RELU) c = fmaxf(c, 0.0f);
        if (OUT == 0) {
          Cf[(size_t)m * Nd + n] = c;
        } else if (OUT == 1) {
          Ch[swz_idx(m, n)] = f2fh(c);
        } else if (OUT == 2) {
          const int mat = n >> 9, h = (n >> 6) & 7, dk = n & 63;
          const int b_ = m >> 10, s_ = m & (kS - 1);
          Ch[((size_t)mat * kM) * kD +
             (((size_t)(b_ * kH + h) * kS + s_) * kDK + dk)] = f2fh(c);
        } else {
          u16 q = f2bh(__expf(c));
          Ch[(size_t)m * Nd + n] = q;
          acc[fm][fn][r] = bh2f(q);
        }
      }
  if (OUT == 3) {
#pragma unroll
    for (int fm = 0; fm < MF; ++fm)
#pragma unroll
      for (int r = 0; r < 4; ++r) {
        float sv = 0.f;
#pragma unroll
        for (int fn = 0; fn < NF; ++fn) sv += acc[fm][fn][r];
        sv += __shfl_xor(sv, 1); sv += __shfl_xor(sv, 2);
        sv += __shfl_xor(sv, 4); sv += __shfl_xor(sv, 8);
        if (li == 0) plds[wc * BM + wr * (BM / 2) + fm * 16 + g * 4 + r] = sv;
      }
    __syncthreads();
    if (t < BM)
      partials[(size_t)(m0 + t) * gridDim.y + blockIdx.y] = plds[t] + plds[BM + t];
  }
}

// ---------------- MFMA flash attention (fp16, double-buffered K/V staging)
__global__ __launch_bounds__(256)
void attn_kernel(const u16* __restrict__ qg, const u16* __restrict__ kg,
                 const u16* __restrict__ vg, u16* __restrict__ aoh) {
  __shared__ __align__(16) u16 Kt[2][2][64][40];
  __shared__ __align__(16) u16 Vt[2][2][64][40];
  __shared__ __align__(16) u16 Pt[2][64][40];
  const int t = threadIdx.x;
  const int lane = t & 63;
  const int g = lane >> 4, li = lane & 15;
  const int w = t >> 6;
  const int bh = blockIdx.y;
  const int q0 = blockIdx.x * 64;
  const size_t base = (size_t)bh * kS * kDK;
  const int r = t >> 2, dq = (t & 3) * 16;

  // stage Q via Pt scratch, pull per-wave A-frags
  {
    const u16* src = &qg[base + (size_t)(q0 + r) * kDK + dq];
    u16x8 a = *(const u16x8*)src;
    u16x8 b = *(const u16x8*)(src + 8);
    *(u16x8*)&Pt[dq >> 5][r][dq & 31] = a;
    *(u16x8*)&Pt[dq >> 5][r][(dq & 31) + 8] = b;
  }
  __syncthreads();
  f16x8 qf0 = *(const f16x8*)&Pt[0][w * 16 + li][g * 8];
  f16x8 qf1 = *(const f16x8*)&Pt[1][w * 16 + li][g * 8];
  __syncthreads();   // Pt free for P tiles

  float m_[4] = {-1e30f, -1e30f, -1e30f, -1e30f};
  float l_[4] = {0.f, 0.f, 0.f, 0.f};
  f32x4 apv[4];
#pragma unroll
  for (int i = 0; i < 4; ++i) apv[i] = (f32x4){0.f, 0.f, 0.f, 0.f};

  u16x8 ka, kb, va, vb;
  auto load_tile = [&](int kt) {
    const u16* ks = &kg[base + (size_t)(kt * 64 + r) * kDK + dq];
    ka = *(const u16x8*)ks;
    kb = *(const u16x8*)(ks + 8);
    const u16* vs = &vg[base + (size_t)(kt * 64 + r) * kDK + dq];
    va = *(const u16x8*)vs;
    vb = *(const u16x8*)(vs + 8);
  };
  auto store_tile = [&](int c) {
    *(u16x8*)&Kt[c][dq >> 5][r][dq & 31] = ka;
    *(u16x8*)&Kt[c][dq >> 5][r][(dq & 31) + 8] = kb;
    const int vc = r >> 5, ko = (r & 31) >> 3, kp = r & 7;
#pragma unroll
    for (int i = 0; i < 8; ++i) {
      const int d = dq + i;
      Vt[c][vc][d][((ko ^ (d >> 4)) << 3) | kp] = va[i];
    }
#pragma unroll
    for (int i = 0; i < 8; ++i) {
      const int d = dq + 8 + i;
      Vt[c][vc][d][((ko ^ (d >> 4)) << 3) | kp] = vb[i];
    }
  };

  load_tile(0);
  store_tile(0);
  for (int kt = 0; kt < kS / 64; ++kt) {
    const int c = kt & 1;
    if (kt < kS / 64 - 1) load_tile(kt + 1);   // issue next-tile loads early
    __syncthreads();                            // buf c ready
    f32x4 s[4];
#pragma unroll
    for (int nf = 0; nf < 4; ++nf) {
      f16x8 k0 = *(const f16x8*)&Kt[c][0][nf * 16 + li][g * 8];
      f16x8 k1 = *(const f16x8*)&Kt[c][1][nf * 16 + li][g * 8];
      f32x4 sa = (f32x4){0.f, 0.f, 0.f, 0.f};
      sa = __builtin_amdgcn_mfma_f32_16x16x32_f16(qf0, k0, sa, 0, 0, 0);
      sa = __builtin_amdgcn_mfma_f32_16x16x32_f16(qf1, k1, sa, 0, 0, 0);
      s[nf] = sa;
    }
    float corr[4];
#pragma unroll
    for (int rr = 0; rr < 4; ++rr) {
      float tm = fmaxf(fmaxf(s[0][rr], s[1][rr]), fmaxf(s[2][rr], s[3][rr])) * 0.125f;
      tm = fmaxf(tm, __shfl_xor(tm, 1));
      tm = fmaxf(tm, __shfl_xor(tm, 2));
      tm = fmaxf(tm, __shfl_xor(tm, 4));
      tm = fmaxf(tm, __shfl_xor(tm, 8));
      const float nm = fmaxf(m_[rr], tm);
      corr[rr] = __expf(m_[rr] - nm);
      m_[rr] = nm;
    }
    float tsum[4] = {0.f, 0.f, 0.f, 0.f};
    u16 pb[4][4];
#pragma unroll
    for (int nf = 0; nf < 4; ++nf)
#pragma unroll
      for (int rr = 0; rr < 4; ++rr) {
        float p = __expf(s[nf][rr] * 0.125f - m_[rr]);
        tsum[rr] += p;
        pb[nf][rr] = f2fh(p);
      }
#pragma unroll
    for (int rr = 0; rr < 4; ++rr) {
      float ts = tsum[rr];
      ts += __shfl_xor(ts, 1); ts += __shfl_xor(ts, 2);
      ts += __shfl_xor(ts, 4); ts += __shfl_xor(ts, 8);
      l_[rr] = l_[rr] * corr[rr] + ts;
#pragma unroll
      for (int nf = 0; nf < 4; ++nf) apv[nf][rr] *= corr[rr];
    }
#pragma unroll
    for (int nf = 0; nf < 4; ++nf)
#pragma unroll
      for (int rr = 0; rr < 4; ++rr)
        Pt[nf >> 1][w * 16 + g * 4 + rr][(nf & 1) * 16 + li] = pb[nf][rr];
    f16x8 p0 = *(const f16x8*)&Pt[0][w * 16 + li][g * 8];
    f16x8 p1 = *(const f16x8*)&Pt[1][w * 16 + li][g * 8];
#pragma unroll
    for (int nf = 0; nf < 4; ++nf) {
      f16x8 v0 = *(const f16x8*)&Vt[c][0][nf * 16 + li][((g ^ nf) & 3) * 8];
      f16x8 v1 = *(const f16x8*)&Vt[c][1][nf * 16 + li][((g ^ nf) & 3) * 8];
      apv[nf] = __builtin_amdgcn_mfma_f32_16x16x32_f16(p0, v0, apv[nf], 0, 0, 0);
      apv[nf] = __builtin_amdgcn_mfma_f32_16x16x32_f16(p1, v1, apv[nf], 0, 0, 0);
    }
    if (kt < kS / 64 - 1) store_tile(c ^ 1);    // write next tile after compute
  }
  const int b_ = bh >> 3, h_ = bh & 7;
#pragma unroll
  for (int rr = 0; rr < 4; ++rr) {
    const float inv = 1.0f / l_[rr];
    const int row = q0 + w * 16 + g * 4 + rr;
    const int m = b_ * kS + row;
#pragma unroll
    for (int nf = 0; nf < 4; ++nf) {
      const int d = h_ * kDK + nf * 16 + li;
      aoh[swz_idx(m, d)] = f2fh(apv[nf][rr] * inv);
    }
  }
}

// --------------------------------------------- residual + LayerNorm in place
__global__ __launch_bounds__(256)
void ln_kernel(float* __restrict__ x, const float* __restrict__ h,
               const float* __restrict__ gain, const float* __restrict__ bias,
               u16* __restrict__ xh) {
  const int row = blockIdx.x;
  const int s = row & (kS - 1);
  const int t = threadIdx.x;
  float* xr = x + (size_t)row * kD;
  const float* hr = h + (size_t)row * kD;
  const float v0 = xr[t] + hr[t];
  const float v1 = xr[t + 256] + hr[t + 256];
  float sum = v0 + v1;
  float sq = v0 * v0 + v1 * v1;
#pragma unroll
  for (int off = 1; off < 64; off <<= 1) {
    sum += __shfl_xor(sum, off);
    sq += __shfl_xor(sq, off);
  }
  __shared__ float rs[4], rq[4];
  if ((t & 63) == 0) { rs[t >> 6] = sum; rq[t >> 6] = sq; }
  __syncthreads();
  sum = rs[0] + rs[1] + rs[2] + rs[3];
  sq = rq[0] + rq[1] + rq[2] + rq[3];
  const float mean = sum * (1.0f / kD);
  const float var = fmaxf(sq * (1.0f / kD) - mean * mean, 0.0f);
  const float inv = 1.0f / (sqrtf(var) + 1e-6f);
  const float* gr = gain + (size_t)s * kD;
  const float* br = bias + (size_t)s * kD;
  const float o0 = gr[t] * inv * (v0 - mean) + br[t];
  const float o1 = gr[t + 256] * inv * (v1 - mean) + br[t + 256];
  xr[t] = o0;
  xr[t + 256] = o1;
  xh[swz_idx(row, t)] = f2fh(o0);
  xh[swz_idx(row, t + 256)] = f2fh(o1);
}

// ---------------- fused rowsum + scale: p = bf16exp / sum, write fp32 d_out
__global__ __launch_bounds__(256)
void scale_kernel(const u16* __restrict__ expb, const float* __restrict__ partials,
                  float* __restrict__ out) {
  const int row = blockIdx.x;
  const int t = threadIdx.x;
  float s = (t < kNB) ? partials[(size_t)row * kNB + t] : 0.f;
#pragma unroll
  for (int off = 1; off < 64; off <<= 1) s += __shfl_xor(s, off);
  __shared__ float red[4];
  if ((t & 63) == 0) red[t >> 6] = s;
  __syncthreads();
  const float inv = 1.0f / (red[0] + red[1] + red[2] + red[3]);
  const u16x8* src = (const u16x8*)(expb + (size_t)row * kV);
  float4* dst = (float4*)(out + (size_t)row * kV);
  for (int i = t; i < kV / 8; i += 256) {
    u16x8 v = src[i];
    float4 a = make_float4(bh2f(v[0]) * inv, bh2f(v[1]) * inv,
                           bh2f(v[2]) * inv, bh2f(v[3]) * inv);
    float4 b = make_float4(bh2f(v[4]) * inv, bh2f(v[5]) * inv,
                           bh2f(v[6]) * inv, bh2f(v[7]) * inv);
    dst[i * 2] = a;
    dst[i * 2 + 1] = b;
  }
}

// ---------------------------------------------------------------------------
extern "C" void kernel_launch(void* const* d_in, const int* in_sizes, int n_in,
                              void* d_out, int out_size, void* d_ws, size_t ws_size,
                              hipStream_t stream) {
  (void)in_sizes; (void)n_in; (void)out_size; (void)ws_size;
  const int* tokens = (const int*)d_in[0];
  const float* emb = (const float*)d_in[1];
  const float* Wq = (const float*)d_in[2];
  const float* Wk = (const float*)d_in[3];
  const float* Wv = (const float*)d_in[4];
  const float* Wo = (const float*)d_in[5];
  const float* lng = (const float*)d_in[6];
  const float* lnb = (const float*)d_in[7];
  const float* w1 = (const float*)d_in[8];
  const float* b1 = (const float*)d_in[9];
  const float* w2 = (const float*)d_in[10];
  const float* b2 = (const float*)d_in[11];

  size_t off = 0;
  auto alloc = [&](size_t bytes) {
    void* p = (char*)d_ws + off;
    off += (bytes + 255) & ~(size_t)255;
    return p;
  };
  const size_t NA = (size_t)kM * kD;
  float* x = (float*)alloc(NA * 4);
  u16* xh = (u16*)alloc(NA * 2);
  u16* qkvb = (u16*)alloc(3 * NA * 2);
  u16* aoh = (u16*)alloc(NA * 2);
  float* t1 = (float*)alloc(NA * 4);
  u16* t1h = (u16*)alloc(NA * 2);
  float* ao2 = (float*)alloc(NA * 4);
  float* partials = (float*)alloc((size_t)kM * kNB * 4);
  u16* expb = (u16*)alloc((size_t)kM * kV * 2);     // 131 MB bf16 exp-logits
  u16* wqkvh = (u16*)alloc((size_t)8 * 1536 * kD * 2);
  u16* woh = (u16*)alloc((size_t)8 * kD * kD * 2);
  u16* w1h = (u16*)alloc((size_t)4 * kD * kD * 2);
  u16* w2h = (u16*)alloc((size_t)4 * kD * kD * 2);
  u16* embh = (u16*)alloc((size_t)kV * kD * 2);

  conv_qkv<<<dim3(8, 8, 24), 256, 0, stream>>>(Wq, Wk, Wv, wqkvh);
  conv_sq<<<dim3(8, 8, 16), 256, 0, stream>>>(Wo, w1, w2, woh, w1h, w2h);
  conv_emb<<<kV * kD / 8 / 256, 256, 0, stream>>>(emb, embh);
  embed_kernel<<<kM, 256, 0, stream>>>(tokens, emb, x, xh);

  for (int l = 0; l < kL; ++l) {
    for (int j = 0; j < 2; ++j) {
      const size_t lj = (size_t)(l * 2 + j);
      mgemm2<128, 128, 2, 0, 0><<<dim3(kM / 128, 12), 256, 0, stream>>>(
          xh, wqkvh + lj * 1536 * kD, nullptr, qkvb, nullptr, nullptr, kD, 1536);
      attn_kernel<<<dim3(kS / 64, kB * kH), 256, 0, stream>>>(
          qkvb, qkvb + NA, qkvb + 2 * NA, aoh);
      mgemm2<64, 64, 0, 0, 0><<<dim3(kM / 64, kD / 64), 256, 0, stream>>>(
          aoh, woh + lj * kD * kD, t1, nullptr, nullptr, nullptr, kD, kD);
      ln_kernel<<<kM, 256, 0, stream>>>(x, t1, lng + (size_t)(l * 3 + j) * kS * kD,
                                        lnb + (size_t)(l * 3 + j) * kS * kD, xh);
    }
    mgemm2<64, 64, 1, 1, 1><<<dim3(kM / 64, kD / 64), 256, 0, stream>>>(
        xh, w1h + (size_t)l * kD * kD, nullptr, t1h, b1 + (size_t)l * kD,
        nullptr, kD, kD);
    mgemm2<64, 64, 0, 1, 0><<<dim3(kM / 64, kD / 64), 256, 0, stream>>>(
        t1h, w2h + (size_t)l * kD * kD, ao2, nullptr, b2 + (size_t)l * kD,
        nullptr, kD, kD);
    ln_kernel<<<kM, 256, 0, stream>>>(x, ao2, lng + (size_t)(l * 3 + 2) * kS * kD,
                                      lnb + (size_t)(l * 3 + 2) * kS * kD, xh);
  }
  // vocab: bf16 exp(x @ emb^T) -> expb + partials; then fused rowsum+scale
  mgemm2<128, 128, 3, 0, 0><<<dim3(kM / 128, kNB), 256, 0, stream>>>(
      xh, embh, nullptr, expb, nullptr, partials, kD, kV);
  scale_kernel<<<kM, 256, 0, stream>>>(expb, partials, (float*)d_out);
}